// Round 1
// baseline (809.469 us; speedup 1.0000x reference)
//
#include <hip/hip_runtime.h>
#include <cstdint>
#include <cstddef>

#define B_ 2
#define S_ 2048
#define HID_ 1024
#define NH_ 8
#define NKV_ 2
#define HD_ 256
#define ROT_ 128
#define TOK_ (B_ * S_)
#define SCALE_ 0.0625f

typedef __attribute__((ext_vector_type(8))) short s16x8;
typedef __attribute__((ext_vector_type(4))) float f32x4;

__device__ __forceinline__ float bf2f(short u) {
  unsigned t = ((unsigned)(unsigned short)u) << 16;
  float f;
  __builtin_memcpy(&f, &t, 4);
  return f;
}
__device__ __forceinline__ short f2bf(float f) {
  unsigned u;
  __builtin_memcpy(&u, &f, 4);
  u += 0x7fffu + ((u >> 16) & 1);
  return (short)(u >> 16);
}

// ---------------- elementwise cast fp32 -> bf16 ----------------
__global__ __launch_bounds__(256) void k_cast(const float* __restrict__ in,
                                              short* __restrict__ out, int n) {
  int i = blockIdx.x * 256 + threadIdx.x;
  if (i < n) out[i] = f2bf(in[i]);
}

// ---------------- transpose + cast: in[R][C] fp32 -> out[C][R] bf16 ----------------
__global__ __launch_bounds__(256) void k_transpose(const float* __restrict__ in,
                                                   short* __restrict__ out, int R, int C) {
  int i = blockIdx.x * 256 + threadIdx.x;
  if (i >= R * C) return;
  int n = i / R, k = i - n * R;
  out[i] = f2bf(in[(size_t)k * C + n]);
}

// ---------------- GEMM: C[M][N] = A[M][K] (bf16) @ Bt[N][K]^T (bf16) ----------------
// 128x128 tile, BK=32, 4 waves each computing a 64x64 sub-tile (4x4 frags of 16x16x32).
template <int OUT_BF16>
__global__ __launch_bounds__(256) void k_gemm_bt(const short* __restrict__ A,
                                                 const short* __restrict__ Bt,
                                                 void* __restrict__ Cv, int M, int N, int K) {
  __shared__ short As[128][40];  // +8 pad: row stride 80B breaks bank aliasing
  __shared__ short Bs[128][40];
  const int tid = threadIdx.x;
  const int bm = blockIdx.y * 128, bn = blockIdx.x * 128;
  const int w = tid >> 6, lane = tid & 63, lo = lane & 15, hi = lane >> 4;
  const int wr = (w >> 1) * 64, wc = (w & 1) * 64;
  f32x4 acc[4][4] = {};
  for (int k0 = 0; k0 < K; k0 += 32) {
    __syncthreads();
#pragma unroll
    for (int c = 0; c < 2; ++c) {
      int e = c * 2048 + tid * 8;
      int row = e >> 5, col = e & 31;
      *(s16x8*)&As[row][col] = *(const s16x8*)&A[(size_t)(bm + row) * K + k0 + col];
      *(s16x8*)&Bs[row][col] = *(const s16x8*)&Bt[(size_t)(bn + row) * K + k0 + col];
    }
    __syncthreads();
    s16x8 af[4], bfr[4];
#pragma unroll
    for (int m = 0; m < 4; ++m) af[m] = *(const s16x8*)&As[wr + m * 16 + lo][hi * 8];
#pragma unroll
    for (int n = 0; n < 4; ++n) bfr[n] = *(const s16x8*)&Bs[wc + n * 16 + lo][hi * 8];
#pragma unroll
    for (int m = 0; m < 4; ++m)
#pragma unroll
      for (int n = 0; n < 4; ++n)
        acc[m][n] = __builtin_amdgcn_mfma_f32_16x16x32_bf16(af[m], bfr[n], acc[m][n], 0, 0, 0);
  }
#pragma unroll
  for (int m = 0; m < 4; ++m)
#pragma unroll
    for (int n = 0; n < 4; ++n)
#pragma unroll
      for (int r = 0; r < 4; ++r) {
        int row = bm + wr + m * 16 + hi * 4 + r;  // C/D layout: col=lane&15, row=(lane>>4)*4+r
        int col = bn + wc + n * 16 + lo;
        if (OUT_BF16)
          ((short*)Cv)[(size_t)row * N + col] = f2bf(acc[m][n][r]);
        else
          ((float*)Cv)[(size_t)row * N + col] = acc[m][n][r];
      }
}

// ---------------- per-(token,head) RMSNorm + RoPE, bf16 in/out ----------------
// in element: ts*IN_ROW + h*IN_HS + d ; out element: (ts*NHEAD + h)*256 + d
template <int NHEAD, int IN_ROW, int IN_HS>
__global__ __launch_bounds__(256) void k_norm_rope(const short* __restrict__ xin,
                                                   const float* __restrict__ wn,
                                                   const float* __restrict__ cosb,
                                                   const float* __restrict__ sinb,
                                                   short* __restrict__ xout) {
  int blk = blockIdx.x;
  int h = blk % NHEAD;
  int ts = blk / NHEAD;
  int d = threadIdx.x;
  float x = bf2f(xin[(size_t)ts * IN_ROW + h * IN_HS + d]);
  float ss = x * x;
#pragma unroll
  for (int m = 32; m >= 1; m >>= 1) ss += __shfl_xor(ss, m);
  __shared__ float sred[4];
  __shared__ float sn[256];
  int wid = d >> 6;
  if ((d & 63) == 0) sred[wid] = ss;
  __syncthreads();
  float tot = sred[0] + sred[1] + sred[2] + sred[3];
  float nv = x * rsqrtf(tot * (1.0f / 256.0f) + 1e-6f) * (1.0f + wn[d]);
  sn[d] = nv;
  __syncthreads();
  float o;
  if (d < 128) {
    float c = cosb[(size_t)ts * 128 + d];
    float s = sinb[(size_t)ts * 128 + d];
    o = (d < 64) ? (nv * c - sn[d + 64] * s) : (nv * c + sn[d - 64] * s);
  } else {
    o = nv;
  }
  xout[(size_t)blk * 256 + d] = f2bf(o);
}

// ---------------- GQA causal flash attention + sigmoid gate ----------------
// grid: (S/64 q-tiles, B*NH heads). 4 waves/block, 16 q-rows per wave, KV tile = 32.
__global__ __launch_bounds__(256) void k_attn(const short* __restrict__ qb,
                                              const short* __restrict__ kb,
                                              const short* __restrict__ kvpre,
                                              const short* __restrict__ qg,
                                              short* __restrict__ og) {
  __shared__ short Ks[32][264];      // [kv][hd] +8 pad
  __shared__ short Vt[256][40];      // [hd][kv] +8 pad (transposed V)
  __shared__ short Ps[4][16][40];    // per-wave P tile
  const int qt = blockIdx.x, hg = blockIdx.y;
  const int b = hg >> 3, h = hg & 7, kvh = h >> 2;
  const int q0 = qt * 64;
  const int tid = threadIdx.x;
  const int w = tid >> 6, lane = tid & 63, lo = lane & 15, hi = lane >> 4;

  // Q fragments for this wave's 16 rows: A-layout (m=lane&15, k=(lane>>4)*8+j)
  s16x8 qf[8];
  {
    size_t base = ((size_t)((b * S_ + q0 + w * 16 + lo) * NH_) + h) * HD_;
#pragma unroll
    for (int t = 0; t < 8; ++t) qf[t] = *(const s16x8*)&qb[base + t * 32 + hi * 8];
  }
  f32x4 acc[16] = {};
  float m_run[4], l_run[4];
#pragma unroll
  for (int r = 0; r < 4; ++r) { m_run[r] = -1e30f; l_run[r] = 0.f; }

  const int ntiles = qt * 2 + 2;  // covers kv in [0, q0+64)
  for (int it = 0; it < ntiles; ++it) {
    const int kv0 = it * 32;
    __syncthreads();
    // stage K tile [32][256] and V tile transposed [256][32]
#pragma unroll
    for (int c = 0; c < 4; ++c) {
      int e = c * 2048 + tid * 8;
      int row = e >> 8, col = e & 255;
      *(s16x8*)&Ks[row][col] =
          *(const s16x8*)&kb[((size_t)((b * S_ + kv0 + row) * NKV_) + kvh) * HD_ + col];
      s16x8 vv =
          *(const s16x8*)&kvpre[(size_t)(b * S_ + kv0 + row) * 1024 + 512 + kvh * 256 + col];
#pragma unroll
      for (int j = 0; j < 8; ++j) Vt[col + j][row] = vv[j];
    }
    __syncthreads();

    // S = Q @ K^T over HD=256 (8 k-steps), two 16-col tiles
    f32x4 sacc0 = {}, sacc1 = {};
#pragma unroll
    for (int t = 0; t < 8; ++t) {
      s16x8 kf0 = *(const s16x8*)&Ks[lo][t * 32 + hi * 8];
      s16x8 kf1 = *(const s16x8*)&Ks[16 + lo][t * 32 + hi * 8];
      sacc0 = __builtin_amdgcn_mfma_f32_16x16x32_bf16(qf[t], kf0, sacc0, 0, 0, 0);
      sacc1 = __builtin_amdgcn_mfma_f32_16x16x32_bf16(qf[t], kf1, sacc1, 0, 0, 0);
    }

    // online softmax (rows = hi*4+r, cols = lane&15 within each 16-col tile)
    float fs[4], p0[4], p1[4];
#pragma unroll
    for (int r = 0; r < 4; ++r) {
      int row = q0 + w * 16 + hi * 4 + r;
      float s0 = sacc0[r] * SCALE_;
      float s1 = sacc1[r] * SCALE_;
      if (kv0 + lo > row) s0 = -1e30f;
      if (kv0 + 16 + lo > row) s1 = -1e30f;
      float mx = fmaxf(s0, s1);
#pragma unroll
      for (int m = 8; m >= 1; m >>= 1) mx = fmaxf(mx, __shfl_xor(mx, m));
      float mnew = fmaxf(m_run[r], mx);
      fs[r] = __expf(m_run[r] - mnew);
      m_run[r] = mnew;
      s0 = __expf(s0 - mnew);
      s1 = __expf(s1 - mnew);
      p0[r] = s0;
      p1[r] = s1;
      float rs = s0 + s1;
#pragma unroll
      for (int m = 8; m >= 1; m >>= 1) rs += __shfl_xor(rs, m);
      l_run[r] = l_run[r] * fs[r] + rs;
    }
#pragma unroll
    for (int t = 0; t < 16; ++t) {
      acc[t][0] *= fs[0];
      acc[t][1] *= fs[1];
      acc[t][2] *= fs[2];
      acc[t][3] *= fs[3];
    }
    // route P through per-wave LDS into A-fragment layout
#pragma unroll
    for (int r = 0; r < 4; ++r) {
      Ps[w][hi * 4 + r][lo] = f2bf(p0[r]);
      Ps[w][hi * 4 + r][16 + lo] = f2bf(p1[r]);
    }
    s16x8 pa = *(const s16x8*)&Ps[w][lo][hi * 8];
#pragma unroll
    for (int t = 0; t < 16; ++t) {
      s16x8 vf = *(const s16x8*)&Vt[t * 16 + lo][hi * 8];
      acc[t] = __builtin_amdgcn_mfma_f32_16x16x32_bf16(pa, vf, acc[t], 0, 0, 0);
    }
  }

  // epilogue: normalize, gate with sigmoid, store bf16
  float inv[4];
#pragma unroll
  for (int r = 0; r < 4; ++r) inv[r] = 1.0f / l_run[r];
#pragma unroll
  for (int t = 0; t < 16; ++t)
#pragma unroll
    for (int r = 0; r < 4; ++r) {
      int row = q0 + w * 16 + hi * 4 + r;
      int hd = t * 16 + lo;
      float o = acc[t][r] * inv[r];
      float g = bf2f(qg[(size_t)(b * S_ + row) * 4096 + h * 512 + 256 + hd]);
      float sg = 1.0f / (1.0f + __expf(-g));
      og[(size_t)(b * S_ + row) * 2048 + h * 256 + hd] = f2bf(o * sg);
    }
}

extern "C" void kernel_launch(void* const* d_in, const int* in_sizes, int n_in, void* d_out,
                              int out_size, void* d_ws, size_t ws_size, hipStream_t stream) {
  const float* hidden = (const float*)d_in[0];
  const float* cosb = (const float*)d_in[1];
  const float* sinb = (const float*)d_in[2];
  const float* Wq = (const float*)d_in[3];
  const float* Wk = (const float*)d_in[4];
  const float* Wv = (const float*)d_in[5];
  const float* Wo = (const float*)d_in[6];
  const float* qw = (const float*)d_in[7];
  const float* kw = (const float*)d_in[8];
  float* out = (float*)d_out;

  char* ws = (char*)d_ws;
  size_t off = 0;
  auto alloc = [&](size_t bytes) {
    void* p = ws + off;
    off += (bytes + 255) & ~(size_t)255;
    return p;
  };
  short* hb = (short*)alloc((size_t)TOK_ * HID_ * 2);        // hidden bf16 [4096][1024]
  short* WqT = (short*)alloc((size_t)4096 * 1024 * 2);       // Wq^T bf16 [4096][1024]
  short* kvT = (short*)alloc((size_t)1024 * 1024 * 2);       // [Wk|Wv]^T bf16 [1024][1024]
  short* WoT = (short*)alloc((size_t)1024 * 2048 * 2);       // Wo^T bf16 [1024][2048]
  short* qg = (short*)alloc((size_t)TOK_ * 4096 * 2);        // qgate bf16 [4096][NH][512]
  short* kvp = (short*)alloc((size_t)TOK_ * 1024 * 2);       // k|v pre bf16 [4096][1024]
  short* qb = (short*)alloc((size_t)TOK_ * 2048 * 2);        // q post norm+rope [4096][NH][256]
  short* kb = (short*)alloc((size_t)TOK_ * 512 * 2);         // k post norm+rope [4096][NKV][256]
  short* og = (short*)alloc((size_t)TOK_ * 2048 * 2);        // gated attn out bf16 [4096][2048]
  (void)ws_size;
  (void)in_sizes;
  (void)n_in;
  (void)out_size;

  k_cast<<<(TOK_ * HID_ + 255) / 256, 256, 0, stream>>>(hidden, hb, TOK_ * HID_);
  k_transpose<<<(1024 * 4096 + 255) / 256, 256, 0, stream>>>(Wq, WqT, 1024, 4096);
  k_transpose<<<(1024 * 512 + 255) / 256, 256, 0, stream>>>(Wk, kvT, 1024, 512);
  k_transpose<<<(1024 * 512 + 255) / 256, 256, 0, stream>>>(Wv, kvT + 512 * 1024, 1024, 512);
  k_transpose<<<(2048 * 1024 + 255) / 256, 256, 0, stream>>>(Wo, WoT, 2048, 1024);

  k_gemm_bt<1><<<dim3(32, 32), 256, 0, stream>>>(hb, WqT, qg, 4096, 4096, 1024);
  k_gemm_bt<1><<<dim3(8, 32), 256, 0, stream>>>(hb, kvT, kvp, 4096, 1024, 1024);

  k_norm_rope<NH_, 4096, 512><<<TOK_ * NH_, 256, 0, stream>>>(qg, qw, cosb, sinb, qb);
  k_norm_rope<NKV_, 1024, 256><<<TOK_ * NKV_, 256, 0, stream>>>(kvp, kw, cosb, sinb, kb);

  k_attn<<<dim3(32, 16), 256, 0, stream>>>(qb, kb, kvp, qg, og);

  k_gemm_bt<0><<<dim3(8, 32), 256, 0, stream>>>(og, WoT, out, 4096, 1024, 2048);
}

// Round 2
// 556.364 us; speedup vs baseline: 1.4549x; 1.4549x over previous
//
#include <hip/hip_runtime.h>
#include <cstdint>
#include <cstddef>

#define B_ 2
#define S_ 2048
#define HID_ 1024
#define NH_ 8
#define NKV_ 2
#define HD_ 256
#define ROT_ 128
#define TOK_ (B_ * S_)
#define SCALE_ 0.0625f

typedef __attribute__((ext_vector_type(8))) short s16x8;
typedef __attribute__((ext_vector_type(4))) float f32x4;

__device__ __forceinline__ float bf2f(short u) {
  unsigned t = ((unsigned)(unsigned short)u) << 16;
  float f;
  __builtin_memcpy(&f, &t, 4);
  return f;
}
__device__ __forceinline__ short f2bf(float f) {
  unsigned u;
  __builtin_memcpy(&u, &f, 4);
  u += 0x7fffu + ((u >> 16) & 1);
  return (short)(u >> 16);
}

// ---------------- elementwise cast fp32 -> bf16 ----------------
__global__ __launch_bounds__(256) void k_cast(const float* __restrict__ in,
                                              short* __restrict__ out, int n) {
  int i = blockIdx.x * 256 + threadIdx.x;
  if (i < n) out[i] = f2bf(in[i]);
}

// ---------------- tiled transpose + cast: in[R][C] fp32 -> out[C][R] bf16 ----------------
__global__ __launch_bounds__(256) void k_wtrans(const float* __restrict__ in,
                                                short* __restrict__ out, int R, int C) {
  __shared__ short tile[32][33];
  int tx = threadIdx.x & 31, ty = threadIdx.x >> 5;  // ty 0..7
  int r0 = blockIdx.y * 32, c0 = blockIdx.x * 32;
#pragma unroll
  for (int p = 0; p < 4; ++p)
    tile[ty + p * 8][tx] = f2bf(in[(size_t)(r0 + ty + p * 8) * C + c0 + tx]);
  __syncthreads();
#pragma unroll
  for (int p = 0; p < 4; ++p)
    out[(size_t)(c0 + ty + p * 8) * R + r0 + tx] = tile[tx][ty + p * 8];
}

// ---------------- V transpose: kvp v-part -> Vtg[b*2+kvh][256][2048] bf16 ----------------
__global__ __launch_bounds__(256) void k_vtrans(const short* __restrict__ kvp,
                                                short* __restrict__ Vtg) {
  __shared__ short tile[32][33];
  int bh = blockIdx.z;
  int b = bh >> 1, kvh = bh & 1;
  int s0 = blockIdx.x * 32, d0 = blockIdx.y * 32;
  int tx = threadIdx.x & 31, ty = threadIdx.x >> 5;
#pragma unroll
  for (int p = 0; p < 4; ++p) {
    int sr = ty + p * 8;
    tile[sr][tx] = kvp[(size_t)(b * S_ + s0 + sr) * 1024 + 512 + kvh * 256 + d0 + tx];
  }
  __syncthreads();
#pragma unroll
  for (int p = 0; p < 4; ++p) {
    int dr = ty + p * 8;
    Vtg[((size_t)bh * 256 + d0 + dr) * 2048 + s0 + tx] = tile[tx][dr];
  }
}

// ---------------- GEMM: C[M][N] = A[M][K] (bf16) @ Bt[N][K]^T (bf16) ----------------
template <int OUT_BF16>
__global__ __launch_bounds__(256) void k_gemm_bt(const short* __restrict__ A,
                                                 const short* __restrict__ Bt,
                                                 void* __restrict__ Cv, int M, int N, int K) {
  __shared__ short As[128][40];
  __shared__ short Bs[128][40];
  const int tid = threadIdx.x;
  const int bm = blockIdx.y * 128, bn = blockIdx.x * 128;
  const int w = tid >> 6, lane = tid & 63, lo = lane & 15, hi = lane >> 4;
  const int wr = (w >> 1) * 64, wc = (w & 1) * 64;
  f32x4 acc[4][4] = {};
  for (int k0 = 0; k0 < K; k0 += 32) {
    __syncthreads();
#pragma unroll
    for (int c = 0; c < 2; ++c) {
      int e = c * 2048 + tid * 8;
      int row = e >> 5, col = e & 31;
      *(s16x8*)&As[row][col] = *(const s16x8*)&A[(size_t)(bm + row) * K + k0 + col];
      *(s16x8*)&Bs[row][col] = *(const s16x8*)&Bt[(size_t)(bn + row) * K + k0 + col];
    }
    __syncthreads();
    s16x8 af[4], bfr[4];
#pragma unroll
    for (int m = 0; m < 4; ++m) af[m] = *(const s16x8*)&As[wr + m * 16 + lo][hi * 8];
#pragma unroll
    for (int n = 0; n < 4; ++n) bfr[n] = *(const s16x8*)&Bs[wc + n * 16 + lo][hi * 8];
#pragma unroll
    for (int m = 0; m < 4; ++m)
#pragma unroll
      for (int n = 0; n < 4; ++n)
        acc[m][n] = __builtin_amdgcn_mfma_f32_16x16x32_bf16(af[m], bfr[n], acc[m][n], 0, 0, 0);
  }
#pragma unroll
  for (int m = 0; m < 4; ++m)
#pragma unroll
    for (int n = 0; n < 4; ++n)
#pragma unroll
      for (int r = 0; r < 4; ++r) {
        int row = bm + wr + m * 16 + hi * 4 + r;
        int col = bn + wc + n * 16 + lo;
        if (OUT_BF16)
          ((short*)Cv)[(size_t)row * N + col] = f2bf(acc[m][n][r]);
        else
          ((float*)Cv)[(size_t)row * N + col] = acc[m][n][r];
      }
}

// ---------------- per-(token,head) RMSNorm + RoPE, bf16 in/out ----------------
template <int NHEAD, int IN_ROW, int IN_HS>
__global__ __launch_bounds__(256) void k_norm_rope(const short* __restrict__ xin,
                                                   const float* __restrict__ wn,
                                                   const float* __restrict__ cosb,
                                                   const float* __restrict__ sinb,
                                                   short* __restrict__ xout) {
  int blk = blockIdx.x;
  int h = blk % NHEAD;
  int ts = blk / NHEAD;
  int d = threadIdx.x;
  float x = bf2f(xin[(size_t)ts * IN_ROW + h * IN_HS + d]);
  float ss = x * x;
#pragma unroll
  for (int m = 32; m >= 1; m >>= 1) ss += __shfl_xor(ss, m);
  __shared__ float sred[4];
  __shared__ float sn[256];
  int wid = d >> 6;
  if ((d & 63) == 0) sred[wid] = ss;
  __syncthreads();
  float tot = sred[0] + sred[1] + sred[2] + sred[3];
  float nv = x * rsqrtf(tot * (1.0f / 256.0f) + 1e-6f) * (1.0f + wn[d]);
  sn[d] = nv;
  __syncthreads();
  float o;
  if (d < 128) {
    float c = cosb[(size_t)ts * 128 + d];
    float s = sinb[(size_t)ts * 128 + d];
    o = (d < 64) ? (nv * c - sn[d + 64] * s) : (nv * c + sn[d - 64] * s);
  } else {
    o = nv;
  }
  xout[(size_t)blk * 256 + d] = f2bf(o);
}

// ---------------- GQA causal flash attention + sigmoid gate ----------------
// 4 waves/block, QBLK=64 (16 q-rows/wave), KVBLK=64. V pre-transposed in global.
// Dynamic LDS: Ks[64][264] + Vt[256][72] + Ps[4][16][72] = 79872 B -> 2 blocks/CU.
#define ATTN_LDS (33792 + 36864 + 9216)
__global__ __launch_bounds__(256) void k_attn(const short* __restrict__ qb,
                                              const short* __restrict__ kb,
                                              const short* __restrict__ Vtg,
                                              const short* __restrict__ qg,
                                              short* __restrict__ og) {
  extern __shared__ char smem[];
  short(*Ks)[264] = (short(*)[264])smem;                      // [kv][hd], +8 pad
  short(*Vt)[72] = (short(*)[72])(smem + 33792);              // [hd][kv], +8 pad
  short(*Ps)[16][72] = (short(*)[16][72])(smem + 33792 + 36864);  // per-wave P

  // causal load-balance: blocks bx and bx+256 get complementary qt (sum = 33 iters)
  const int half = blockIdx.x >> 8;
  const int rr = blockIdx.x & 255;
  const int hg = (rr >> 5) | (half << 3);
  const int qt = half ? (31 - (rr & 31)) : (rr & 31);
  const int b = hg >> 3, h = hg & 7, kvh = h >> 2;
  const int q0 = qt * 64;
  const int tid = threadIdx.x;
  const int w = tid >> 6, lane = tid & 63, lo = lane & 15, hi = lane >> 4;

  // Q fragments: A-layout (m=lane&15 -> q-row, k=(lane>>4)*8+j)
  s16x8 qf[8];
  {
    size_t base = ((size_t)((b * S_ + q0 + w * 16 + lo) * NH_) + h) * HD_;
#pragma unroll
    for (int t = 0; t < 8; ++t) qf[t] = *(const s16x8*)&qb[base + t * 32 + hi * 8];
  }
  f32x4 acc[16] = {};
  float m_run[4], l_run[4];
#pragma unroll
  for (int r = 0; r < 4; ++r) { m_run[r] = -1e30f; l_run[r] = 0.f; }

  const int ntiles = qt + 1;  // KVBLK=64 covers [0, q0+64)
  for (int it = 0; it < ntiles; ++it) {
    const int kv0 = it * 64;
    const bool last = (it == ntiles - 1);
    const int nlim = last ? (w + 1) : 4;               // QK n-tiles needed
    const int kslim = last ? ((w * 16 + 15) / 32 + 1) : 2;  // PV k-slices needed
    __syncthreads();
    // stage K [64][256] and V^T [256][64], vectorized 16B
#pragma unroll
    for (int c = 0; c < 8; ++c) {
      int e = c * 2048 + tid * 8;
      int krow = e >> 8, kcol = e & 255;
      *(s16x8*)&Ks[krow][kcol] =
          *(const s16x8*)&kb[((size_t)((b * S_ + kv0 + krow) * NKV_) + kvh) * HD_ + kcol];
      int vrow = e >> 6, vcol = e & 63;
      *(s16x8*)&Vt[vrow][vcol] =
          *(const s16x8*)&Vtg[((size_t)(b * 2 + kvh) * 256 + vrow) * 2048 + kv0 + vcol];
    }
    __syncthreads();

    // S = Q @ K^T over HD=256, 4 n-tiles of 16 kv
    f32x4 sacc[4] = {};
#pragma unroll
    for (int t = 0; t < 8; ++t)
      for (int nt = 0; nt < nlim; ++nt) {
        s16x8 kf = *(const s16x8*)&Ks[nt * 16 + lo][t * 32 + hi * 8];
        sacc[nt] = __builtin_amdgcn_mfma_f32_16x16x32_bf16(qf[t], kf, sacc[nt], 0, 0, 0);
      }

    // online softmax: rows = w*16 + hi*4 + r, cols = kv0 + nt*16 + lo
    float fs[4];
#pragma unroll
    for (int r = 0; r < 4; ++r) {
      int row = q0 + w * 16 + hi * 4 + r;
      float sv[4];
#pragma unroll
      for (int nt = 0; nt < 4; ++nt) {
        float s = sacc[nt][r] * SCALE_;
        if (kv0 + nt * 16 + lo > row) s = -1e30f;
        sv[nt] = s;
      }
      float mx = fmaxf(fmaxf(sv[0], sv[1]), fmaxf(sv[2], sv[3]));
#pragma unroll
      for (int m = 8; m >= 1; m >>= 1) mx = fmaxf(mx, __shfl_xor(mx, m));
      float mnew = fmaxf(m_run[r], mx);
      fs[r] = __expf(m_run[r] - mnew);
      m_run[r] = mnew;
      float rs = 0.f;
#pragma unroll
      for (int nt = 0; nt < 4; ++nt) {
        sv[nt] = __expf(sv[nt] - mnew);
        rs += sv[nt];
      }
#pragma unroll
      for (int m = 8; m >= 1; m >>= 1) rs += __shfl_xor(rs, m);
      l_run[r] = l_run[r] * fs[r] + rs;
#pragma unroll
      for (int nt = 0; nt < 4; ++nt) Ps[w][hi * 4 + r][nt * 16 + lo] = f2bf(sv[nt]);
    }
#pragma unroll
    for (int t = 0; t < 16; ++t) {
      acc[t][0] *= fs[0];
      acc[t][1] *= fs[1];
      acc[t][2] *= fs[2];
      acc[t][3] *= fs[3];
    }
    // PV: A = P rows, B = V^T fragments
    for (int ks = 0; ks < kslim; ++ks) {
      s16x8 pa = *(const s16x8*)&Ps[w][lo][ks * 32 + hi * 8];
#pragma unroll
      for (int t = 0; t < 16; ++t) {
        s16x8 vf = *(const s16x8*)&Vt[t * 16 + lo][ks * 32 + hi * 8];
        acc[t] = __builtin_amdgcn_mfma_f32_16x16x32_bf16(pa, vf, acc[t], 0, 0, 0);
      }
    }
  }

  // epilogue: normalize, sigmoid gate, store bf16
  float inv[4];
#pragma unroll
  for (int r = 0; r < 4; ++r) inv[r] = 1.0f / l_run[r];
#pragma unroll
  for (int t = 0; t < 16; ++t)
#pragma unroll
    for (int r = 0; r < 4; ++r) {
      int row = q0 + w * 16 + hi * 4 + r;
      int hd = t * 16 + lo;
      float o = acc[t][r] * inv[r];
      float g = bf2f(qg[(size_t)(b * S_ + row) * 4096 + h * 512 + 256 + hd]);
      float sg = 1.0f / (1.0f + __expf(-g));
      og[(size_t)(b * S_ + row) * 2048 + h * 256 + hd] = f2bf(o * sg);
    }
}

extern "C" void kernel_launch(void* const* d_in, const int* in_sizes, int n_in, void* d_out,
                              int out_size, void* d_ws, size_t ws_size, hipStream_t stream) {
  const float* hidden = (const float*)d_in[0];
  const float* cosb = (const float*)d_in[1];
  const float* sinb = (const float*)d_in[2];
  const float* Wq = (const float*)d_in[3];
  const float* Wk = (const float*)d_in[4];
  const float* Wv = (const float*)d_in[5];
  const float* Wo = (const float*)d_in[6];
  const float* qw = (const float*)d_in[7];
  const float* kw = (const float*)d_in[8];
  float* out = (float*)d_out;

  char* ws = (char*)d_ws;
  size_t off = 0;
  auto alloc = [&](size_t bytes) {
    void* p = ws + off;
    off += (bytes + 255) & ~(size_t)255;
    return p;
  };
  short* hb = (short*)alloc((size_t)TOK_ * HID_ * 2);
  short* WqT = (short*)alloc((size_t)4096 * 1024 * 2);
  short* kvT = (short*)alloc((size_t)1024 * 1024 * 2);
  short* WoT = (short*)alloc((size_t)1024 * 2048 * 2);
  short* qg = (short*)alloc((size_t)TOK_ * 4096 * 2);
  short* kvp = (short*)alloc((size_t)TOK_ * 1024 * 2);
  short* qb = (short*)alloc((size_t)TOK_ * 2048 * 2);
  short* kb = (short*)alloc((size_t)TOK_ * 512 * 2);
  short* og = (short*)alloc((size_t)TOK_ * 2048 * 2);
  short* Vtg = WqT;  // reuse: WqT dead after GEMM1; Vtg (4MB) written after
  (void)ws_size;
  (void)in_sizes;
  (void)n_in;
  (void)out_size;

  hipFuncSetAttribute((const void*)k_attn, hipFuncAttributeMaxDynamicSharedMemorySize, 131072);

  k_cast<<<(TOK_ * HID_ + 255) / 256, 256, 0, stream>>>(hidden, hb, TOK_ * HID_);
  k_wtrans<<<dim3(4096 / 32, 1024 / 32), 256, 0, stream>>>(Wq, WqT, 1024, 4096);
  k_wtrans<<<dim3(512 / 32, 1024 / 32), 256, 0, stream>>>(Wk, kvT, 1024, 512);
  k_wtrans<<<dim3(512 / 32, 1024 / 32), 256, 0, stream>>>(Wv, kvT + 512 * 1024, 1024, 512);
  k_wtrans<<<dim3(1024 / 32, 2048 / 32), 256, 0, stream>>>(Wo, WoT, 2048, 1024);

  k_gemm_bt<1><<<dim3(32, 32), 256, 0, stream>>>(hb, WqT, qg, 4096, 4096, 1024);
  k_gemm_bt<1><<<dim3(8, 32), 256, 0, stream>>>(hb, kvT, kvp, 4096, 1024, 1024);

  k_norm_rope<NH_, 4096, 512><<<TOK_ * NH_, 256, 0, stream>>>(qg, qw, cosb, sinb, qb);
  k_norm_rope<NKV_, 1024, 256><<<TOK_ * NKV_, 256, 0, stream>>>(kvp, kw, cosb, sinb, kb);
  k_vtrans<<<dim3(64, 8, 4), 256, 0, stream>>>(kvp, Vtg);

  k_attn<<<512, 256, ATTN_LDS, stream>>>(qb, kb, Vtg, qg, og);

  k_gemm_bt<0><<<dim3(8, 32), 256, 0, stream>>>(og, WoT, out, 4096, 1024, 2048);
}

// Round 3
// 418.965 us; speedup vs baseline: 1.9321x; 1.3279x over previous
//
#include <hip/hip_runtime.h>
#include <cstdint>
#include <cstddef>

#define B_ 2
#define S_ 2048
#define HID_ 1024
#define NH_ 8
#define NKV_ 2
#define HD_ 256
#define ROT_ 128
#define TOK_ (B_ * S_)
#define SCALE_ 0.0625f

typedef __attribute__((ext_vector_type(8))) short s16x8;
typedef __attribute__((ext_vector_type(4))) float f32x4;

__device__ __forceinline__ float bf2f(short u) {
  unsigned t = ((unsigned)(unsigned short)u) << 16;
  float f;
  __builtin_memcpy(&f, &t, 4);
  return f;
}
__device__ __forceinline__ short f2bf(float f) {
  unsigned u;
  __builtin_memcpy(&u, &f, 4);
  u += 0x7fffu + ((u >> 16) & 1);
  return (short)(u >> 16);
}

// ---------------- elementwise cast fp32 -> bf16 ----------------
__global__ __launch_bounds__(256) void k_cast(const float* __restrict__ in,
                                              short* __restrict__ out, int n) {
  int i = blockIdx.x * 256 + threadIdx.x;
  if (i < n) out[i] = f2bf(in[i]);
}

// ---------------- tiled transpose + cast: in[R][C] fp32 -> out[C][R] bf16 ----------------
__global__ __launch_bounds__(256) void k_wtrans(const float* __restrict__ in,
                                                short* __restrict__ out, int R, int C) {
  __shared__ short tile[32][33];
  int tx = threadIdx.x & 31, ty = threadIdx.x >> 5;
  int r0 = blockIdx.y * 32, c0 = blockIdx.x * 32;
#pragma unroll
  for (int p = 0; p < 4; ++p)
    tile[ty + p * 8][tx] = f2bf(in[(size_t)(r0 + ty + p * 8) * C + c0 + tx]);
  __syncthreads();
#pragma unroll
  for (int p = 0; p < 4; ++p)
    out[(size_t)(c0 + ty + p * 8) * R + r0 + tx] = tile[tx][ty + p * 8];
}

// ---------------- V transpose: kvp v-part -> Vtg[b*2+kvh][256][2048] bf16 ----------------
__global__ __launch_bounds__(256) void k_vtrans(const short* __restrict__ kvp,
                                                short* __restrict__ Vtg) {
  __shared__ short tile[32][33];
  int bh = blockIdx.z;
  int b = bh >> 1, kvh = bh & 1;
  int s0 = blockIdx.x * 32, d0 = blockIdx.y * 32;
  int tx = threadIdx.x & 31, ty = threadIdx.x >> 5;
#pragma unroll
  for (int p = 0; p < 4; ++p) {
    int sr = ty + p * 8;
    tile[sr][tx] = kvp[(size_t)(b * S_ + s0 + sr) * 1024 + 512 + kvh * 256 + d0 + tx];
  }
  __syncthreads();
#pragma unroll
  for (int p = 0; p < 4; ++p) {
    int dr = ty + p * 8;
    Vtg[((size_t)bh * 256 + d0 + dr) * 2048 + s0 + tx] = tile[tx][dr];
  }
}

// ---------------- GEMM: C[M][N] = A[M][K] (bf16) @ Bt[N][K]^T (bf16) ----------------
template <int OUT_BF16>
__global__ __launch_bounds__(256) void k_gemm_bt(const short* __restrict__ A,
                                                 const short* __restrict__ Bt,
                                                 void* __restrict__ Cv, int M, int N, int K) {
  __shared__ short As[128][40];
  __shared__ short Bs[128][40];
  const int tid = threadIdx.x;
  const int bm = blockIdx.y * 128, bn = blockIdx.x * 128;
  const int w = tid >> 6, lane = tid & 63, lo = lane & 15, hi = lane >> 4;
  const int wr = (w >> 1) * 64, wc = (w & 1) * 64;
  f32x4 acc[4][4] = {};
  for (int k0 = 0; k0 < K; k0 += 32) {
    __syncthreads();
#pragma unroll
    for (int c = 0; c < 2; ++c) {
      int e = c * 2048 + tid * 8;
      int row = e >> 5, col = e & 31;
      *(s16x8*)&As[row][col] = *(const s16x8*)&A[(size_t)(bm + row) * K + k0 + col];
      *(s16x8*)&Bs[row][col] = *(const s16x8*)&Bt[(size_t)(bn + row) * K + k0 + col];
    }
    __syncthreads();
    s16x8 af[4], bfr[4];
#pragma unroll
    for (int m = 0; m < 4; ++m) af[m] = *(const s16x8*)&As[wr + m * 16 + lo][hi * 8];
#pragma unroll
    for (int n = 0; n < 4; ++n) bfr[n] = *(const s16x8*)&Bs[wc + n * 16 + lo][hi * 8];
#pragma unroll
    for (int m = 0; m < 4; ++m)
#pragma unroll
      for (int n = 0; n < 4; ++n)
        acc[m][n] = __builtin_amdgcn_mfma_f32_16x16x32_bf16(af[m], bfr[n], acc[m][n], 0, 0, 0);
  }
#pragma unroll
  for (int m = 0; m < 4; ++m)
#pragma unroll
    for (int n = 0; n < 4; ++n)
#pragma unroll
      for (int r = 0; r < 4; ++r) {
        int row = bm + wr + m * 16 + hi * 4 + r;
        int col = bn + wc + n * 16 + lo;
        if (OUT_BF16)
          ((short*)Cv)[(size_t)row * N + col] = f2bf(acc[m][n][r]);
        else
          ((float*)Cv)[(size_t)row * N + col] = acc[m][n][r];
      }
}

// ---------------- per-(token,head) RMSNorm + RoPE, bf16 in/out ----------------
template <int NHEAD, int IN_ROW, int IN_HS>
__global__ __launch_bounds__(256) void k_norm_rope(const short* __restrict__ xin,
                                                   const float* __restrict__ wn,
                                                   const float* __restrict__ cosb,
                                                   const float* __restrict__ sinb,
                                                   short* __restrict__ xout) {
  int blk = blockIdx.x;
  int h = blk % NHEAD;
  int ts = blk / NHEAD;
  int d = threadIdx.x;
  float x = bf2f(xin[(size_t)ts * IN_ROW + h * IN_HS + d]);
  float ss = x * x;
#pragma unroll
  for (int m = 32; m >= 1; m >>= 1) ss += __shfl_xor(ss, m);
  __shared__ float sred[4];
  __shared__ float sn[256];
  int wid = d >> 6;
  if ((d & 63) == 0) sred[wid] = ss;
  __syncthreads();
  float tot = sred[0] + sred[1] + sred[2] + sred[3];
  float nv = x * rsqrtf(tot * (1.0f / 256.0f) + 1e-6f) * (1.0f + wn[d]);
  sn[d] = nv;
  __syncthreads();
  float o;
  if (d < 128) {
    float c = cosb[(size_t)ts * 128 + d];
    float s = sinb[(size_t)ts * 128 + d];
    o = (d < 64) ? (nv * c - sn[d + 64] * s) : (nv * c + sn[d - 64] * s);
  } else {
    o = nv;
  }
  xout[(size_t)blk * 256 + d] = f2bf(o);
}

// ---------------- GQA causal flash attention + sigmoid gate ----------------
// 4 waves/block, QBLK=64 (16 q-rows/wave), KVBLK=64. V pre-transposed in global.
// All inner loops have STATIC bounds (runtime bounds -> acc arrays demoted to scratch).
// T14 async-stage: prefetch next K/V tile into regs before compute, ds_write after barrier.
#define ATTN_LDS (33792 + 36864 + 9216)
__global__ __launch_bounds__(256) void k_attn(const short* __restrict__ qb,
                                              const short* __restrict__ kb,
                                              const short* __restrict__ Vtg,
                                              const short* __restrict__ qg,
                                              short* __restrict__ og) {
  extern __shared__ char smem[];
  short(*Ks)[264] = (short(*)[264])smem;                          // [kv][hd], +8 pad
  short(*Vt)[72] = (short(*)[72])(smem + 33792);                  // [hd][kv], +8 pad
  short(*Ps)[16][72] = (short(*)[16][72])(smem + 33792 + 36864);  // per-wave P

  // causal load-balance: blocks bx and bx+256 get complementary qt (sum = 33 iters)
  const int half = blockIdx.x >> 8;
  const int rr = blockIdx.x & 255;
  const int hg = (rr >> 5) | (half << 3);
  const int qt = half ? (31 - (rr & 31)) : (rr & 31);
  const int b = hg >> 3, h = hg & 7, kvh = h >> 2;
  const int q0 = qt * 64;
  const int tid = threadIdx.x;
  const int w = tid >> 6, lane = tid & 63, lo = lane & 15, hi = lane >> 4;

  const short* kbase = kb + ((size_t)(b * S_) * NKV_ + kvh) * HD_;  // row stride 512
  const short* vbase = Vtg + (size_t)(b * 2 + kvh) * 256 * 2048;

  // Q fragments: A-layout (m=lane&15 -> q-row, k=(lane>>4)*8+j)
  s16x8 qf[8];
  {
    size_t base = ((size_t)((b * S_ + q0 + w * 16 + lo) * NH_) + h) * HD_;
#pragma unroll
    for (int t = 0; t < 8; ++t) qf[t] = *(const s16x8*)&qb[base + t * 32 + hi * 8];
  }
  f32x4 acc[16] = {};
  float m_run[4], l_run[4];
#pragma unroll
  for (int r = 0; r < 4; ++r) { m_run[r] = -1e30f; l_run[r] = 0.f; }

  s16x8 kr[8], vr[8];
  // prologue: stage tile 0
#pragma unroll
  for (int c = 0; c < 8; ++c) {
    int e = c * 2048 + tid * 8;
    kr[c] = *(const s16x8*)&kbase[(size_t)(e >> 8) * 512 + (e & 255)];
    vr[c] = *(const s16x8*)&vbase[(size_t)(e >> 6) * 2048 + (e & 63)];
  }
#pragma unroll
  for (int c = 0; c < 8; ++c) {
    int e = c * 2048 + tid * 8;
    *(s16x8*)&Ks[e >> 8][e & 255] = kr[c];
    *(s16x8*)&Vt[e >> 6][e & 63] = vr[c];
  }
  __syncthreads();

  const int ntiles = qt + 1;  // KVBLK=64 covers [0, q0+64)
  for (int it = 0; it < ntiles; ++it) {
    const int kv0 = it * 64;
    const bool have_next = (it + 1 < ntiles);
    // T14: issue next tile's global loads now; latency hides under compute below
    if (have_next) {
      const int nkv = kv0 + 64;
#pragma unroll
      for (int c = 0; c < 8; ++c) {
        int e = c * 2048 + tid * 8;
        kr[c] = *(const s16x8*)&kbase[(size_t)(nkv + (e >> 8)) * 512 + (e & 255)];
        vr[c] = *(const s16x8*)&vbase[(size_t)(e >> 6) * 2048 + nkv + (e & 63)];
      }
    }

    // S = Q @ K^T over HD=256, 4 n-tiles of 16 kv — all bounds static
    f32x4 sacc[4] = {};
#pragma unroll
    for (int t = 0; t < 8; ++t)
#pragma unroll
      for (int nt = 0; nt < 4; ++nt) {
        s16x8 kf = *(const s16x8*)&Ks[nt * 16 + lo][t * 32 + hi * 8];
        sacc[nt] = __builtin_amdgcn_mfma_f32_16x16x32_bf16(qf[t], kf, sacc[nt], 0, 0, 0);
      }

    // online softmax: rows = w*16 + hi*4 + r, cols = kv0 + nt*16 + lo
    float fs[4];
#pragma unroll
    for (int r = 0; r < 4; ++r) {
      int row = q0 + w * 16 + hi * 4 + r;
      float sv[4];
#pragma unroll
      for (int nt = 0; nt < 4; ++nt) {
        float s = sacc[nt][r] * SCALE_;
        if (kv0 + nt * 16 + lo > row) s = -1e30f;
        sv[nt] = s;
      }
      float mx = fmaxf(fmaxf(sv[0], sv[1]), fmaxf(sv[2], sv[3]));
#pragma unroll
      for (int m = 8; m >= 1; m >>= 1) mx = fmaxf(mx, __shfl_xor(mx, m));
      float mnew = fmaxf(m_run[r], mx);
      fs[r] = __expf(m_run[r] - mnew);
      m_run[r] = mnew;
      float rs = 0.f;
#pragma unroll
      for (int nt = 0; nt < 4; ++nt) {
        sv[nt] = __expf(sv[nt] - mnew);
        rs += sv[nt];
      }
#pragma unroll
      for (int m = 8; m >= 1; m >>= 1) rs += __shfl_xor(rs, m);
      l_run[r] = l_run[r] * fs[r] + rs;
#pragma unroll
      for (int nt = 0; nt < 4; ++nt) Ps[w][hi * 4 + r][nt * 16 + lo] = f2bf(sv[nt]);
    }
#pragma unroll
    for (int t = 0; t < 16; ++t) {
      acc[t][0] *= fs[0];
      acc[t][1] *= fs[1];
      acc[t][2] *= fs[2];
      acc[t][3] *= fs[3];
    }
    // PV: A = P rows, B = V^T fragments — static bounds
#pragma unroll
    for (int ks = 0; ks < 2; ++ks) {
      s16x8 pa = *(const s16x8*)&Ps[w][lo][ks * 32 + hi * 8];
#pragma unroll
      for (int t = 0; t < 16; ++t) {
        s16x8 vf = *(const s16x8*)&Vt[t * 16 + lo][ks * 32 + hi * 8];
        acc[t] = __builtin_amdgcn_mfma_f32_16x16x32_bf16(pa, vf, acc[t], 0, 0, 0);
      }
    }

    if (have_next) {
      __syncthreads();  // all waves done reading current tile
#pragma unroll
      for (int c = 0; c < 8; ++c) {
        int e = c * 2048 + tid * 8;
        *(s16x8*)&Ks[e >> 8][e & 255] = kr[c];
        *(s16x8*)&Vt[e >> 6][e & 63] = vr[c];
      }
      __syncthreads();  // next tile visible
    }
  }

  // epilogue: normalize, sigmoid gate, store bf16
  float inv[4];
#pragma unroll
  for (int r = 0; r < 4; ++r) inv[r] = 1.0f / l_run[r];
#pragma unroll
  for (int t = 0; t < 16; ++t)
#pragma unroll
    for (int r = 0; r < 4; ++r) {
      int row = q0 + w * 16 + hi * 4 + r;
      int hd = t * 16 + lo;
      float o = acc[t][r] * inv[r];
      float g = bf2f(qg[(size_t)(b * S_ + row) * 4096 + h * 512 + 256 + hd]);
      float sg = 1.0f / (1.0f + __expf(-g));
      og[(size_t)(b * S_ + row) * 2048 + h * 256 + hd] = f2bf(o * sg);
    }
}

extern "C" void kernel_launch(void* const* d_in, const int* in_sizes, int n_in, void* d_out,
                              int out_size, void* d_ws, size_t ws_size, hipStream_t stream) {
  const float* hidden = (const float*)d_in[0];
  const float* cosb = (const float*)d_in[1];
  const float* sinb = (const float*)d_in[2];
  const float* Wq = (const float*)d_in[3];
  const float* Wk = (const float*)d_in[4];
  const float* Wv = (const float*)d_in[5];
  const float* Wo = (const float*)d_in[6];
  const float* qw = (const float*)d_in[7];
  const float* kw = (const float*)d_in[8];
  float* out = (float*)d_out;

  char* ws = (char*)d_ws;
  size_t off = 0;
  auto alloc = [&](size_t bytes) {
    void* p = ws + off;
    off += (bytes + 255) & ~(size_t)255;
    return p;
  };
  short* hb = (short*)alloc((size_t)TOK_ * HID_ * 2);
  short* WqT = (short*)alloc((size_t)4096 * 1024 * 2);
  short* kvT = (short*)alloc((size_t)1024 * 1024 * 2);
  short* WoT = (short*)alloc((size_t)1024 * 2048 * 2);
  short* qg = (short*)alloc((size_t)TOK_ * 4096 * 2);
  short* kvp = (short*)alloc((size_t)TOK_ * 1024 * 2);
  short* qb = (short*)alloc((size_t)TOK_ * 2048 * 2);
  short* kb = (short*)alloc((size_t)TOK_ * 512 * 2);
  short* og = (short*)alloc((size_t)TOK_ * 2048 * 2);
  short* Vtg = WqT;  // reuse: WqT dead after GEMM1
  (void)ws_size;
  (void)in_sizes;
  (void)n_in;
  (void)out_size;

  hipFuncSetAttribute((const void*)k_attn, hipFuncAttributeMaxDynamicSharedMemorySize, 131072);

  k_cast<<<(TOK_ * HID_ + 255) / 256, 256, 0, stream>>>(hidden, hb, TOK_ * HID_);
  k_wtrans<<<dim3(4096 / 32, 1024 / 32), 256, 0, stream>>>(Wq, WqT, 1024, 4096);
  k_wtrans<<<dim3(512 / 32, 1024 / 32), 256, 0, stream>>>(Wk, kvT, 1024, 512);
  k_wtrans<<<dim3(512 / 32, 1024 / 32), 256, 0, stream>>>(Wv, kvT + 512 * 1024, 1024, 512);
  k_wtrans<<<dim3(1024 / 32, 2048 / 32), 256, 0, stream>>>(Wo, WoT, 2048, 1024);

  k_gemm_bt<1><<<dim3(32, 32), 256, 0, stream>>>(hb, WqT, qg, 4096, 4096, 1024);
  k_gemm_bt<1><<<dim3(8, 32), 256, 0, stream>>>(hb, kvT, kvp, 4096, 1024, 1024);

  k_norm_rope<NH_, 4096, 512><<<TOK_ * NH_, 256, 0, stream>>>(qg, qw, cosb, sinb, qb);
  k_norm_rope<NKV_, 1024, 256><<<TOK_ * NKV_, 256, 0, stream>>>(kvp, kw, cosb, sinb, kb);
  k_vtrans<<<dim3(64, 8, 4), 256, 0, stream>>>(kvp, Vtg);

  k_attn<<<512, 256, ATTN_LDS, stream>>>(qb, kb, Vtg, qg, og);

  k_gemm_bt<0><<<dim3(8, 32), 256, 0, stream>>>(og, WoT, out, 4096, 1024, 2048);
}

// Round 4
// 309.659 us; speedup vs baseline: 2.6141x; 1.3530x over previous
//
#include <hip/hip_runtime.h>
#include <cstdint>
#include <cstddef>

#define B_ 2
#define S_ 2048
#define HID_ 1024
#define NH_ 8
#define NKV_ 2
#define HD_ 256
#define ROT_ 128
#define TOK_ (B_ * S_)
#define SCALE_ 0.0625f

typedef __attribute__((ext_vector_type(8))) short s16x8;
typedef __attribute__((ext_vector_type(4))) float f32x4;

__device__ __forceinline__ float bf2f(short u) {
  unsigned t = ((unsigned)(unsigned short)u) << 16;
  float f;
  __builtin_memcpy(&f, &t, 4);
  return f;
}
__device__ __forceinline__ short f2bf(float f) {
  unsigned u;
  __builtin_memcpy(&u, &f, 4);
  u += 0x7fffu + ((u >> 16) & 1);
  return (short)(u >> 16);
}

// async global->LDS 16B (gfx950). LDS dest is wave-uniform base + lane*16.
__device__ __forceinline__ void gl16(const void* g, void* l) {
  __builtin_amdgcn_global_load_lds((const __attribute__((address_space(1))) int*)g,
                                   (__attribute__((address_space(3))) int*)l, 16, 0, 0);
}

// ---------------- elementwise cast fp32 -> bf16 ----------------
__global__ __launch_bounds__(256) void k_cast(const float* __restrict__ in,
                                              short* __restrict__ out, int n) {
  int i = blockIdx.x * 256 + threadIdx.x;
  if (i < n) out[i] = f2bf(in[i]);
}

// ---------------- tiled transpose + cast: in[R][C] fp32 -> out[C][R] bf16 ----------------
__global__ __launch_bounds__(256) void k_wtrans(const float* __restrict__ in,
                                                short* __restrict__ out, int R, int C) {
  __shared__ short tile[32][33];
  int tx = threadIdx.x & 31, ty = threadIdx.x >> 5;
  int r0 = blockIdx.y * 32, c0 = blockIdx.x * 32;
#pragma unroll
  for (int p = 0; p < 4; ++p)
    tile[ty + p * 8][tx] = f2bf(in[(size_t)(r0 + ty + p * 8) * C + c0 + tx]);
  __syncthreads();
#pragma unroll
  for (int p = 0; p < 4; ++p)
    out[(size_t)(c0 + ty + p * 8) * R + r0 + tx] = tile[tx][ty + p * 8];
}

// ---------------- V transpose: kvp v-part -> Vtg[b*2+kvh][256][2048] bf16 ----------------
__global__ __launch_bounds__(256) void k_vtrans(const short* __restrict__ kvp,
                                                short* __restrict__ Vtg) {
  __shared__ short tile[32][33];
  int bh = blockIdx.z;
  int b = bh >> 1, kvh = bh & 1;
  int s0 = blockIdx.x * 32, d0 = blockIdx.y * 32;
  int tx = threadIdx.x & 31, ty = threadIdx.x >> 5;
#pragma unroll
  for (int p = 0; p < 4; ++p) {
    int sr = ty + p * 8;
    tile[sr][tx] = kvp[(size_t)(b * S_ + s0 + sr) * 1024 + 512 + kvh * 256 + d0 + tx];
  }
  __syncthreads();
#pragma unroll
  for (int p = 0; p < 4; ++p) {
    int dr = ty + p * 8;
    Vtg[((size_t)bh * 256 + d0 + dr) * 2048 + s0 + tx] = tile[tx][dr];
  }
}

// ---------------- GEMM: C[M][N] = A[M][K] (bf16) @ Bt[N][K]^T (bf16) ----------------
template <int OUT_BF16>
__global__ __launch_bounds__(256) void k_gemm_bt(const short* __restrict__ A,
                                                 const short* __restrict__ Bt,
                                                 void* __restrict__ Cv, int M, int N, int K) {
  __shared__ short As[128][40];
  __shared__ short Bs[128][40];
  const int tid = threadIdx.x;
  const int bm = blockIdx.y * 128, bn = blockIdx.x * 128;
  const int w = tid >> 6, lane = tid & 63, lo = lane & 15, hi = lane >> 4;
  const int wr = (w >> 1) * 64, wc = (w & 1) * 64;
  f32x4 acc[4][4] = {};
  for (int k0 = 0; k0 < K; k0 += 32) {
    __syncthreads();
#pragma unroll
    for (int c = 0; c < 2; ++c) {
      int e = c * 2048 + tid * 8;
      int row = e >> 5, col = e & 31;
      *(s16x8*)&As[row][col] = *(const s16x8*)&A[(size_t)(bm + row) * K + k0 + col];
      *(s16x8*)&Bs[row][col] = *(const s16x8*)&Bt[(size_t)(bn + row) * K + k0 + col];
    }
    __syncthreads();
    s16x8 af[4], bfr[4];
#pragma unroll
    for (int m = 0; m < 4; ++m) af[m] = *(const s16x8*)&As[wr + m * 16 + lo][hi * 8];
#pragma unroll
    for (int n = 0; n < 4; ++n) bfr[n] = *(const s16x8*)&Bs[wc + n * 16 + lo][hi * 8];
#pragma unroll
    for (int m = 0; m < 4; ++m)
#pragma unroll
      for (int n = 0; n < 4; ++n)
        acc[m][n] = __builtin_amdgcn_mfma_f32_16x16x32_bf16(af[m], bfr[n], acc[m][n], 0, 0, 0);
  }
#pragma unroll
  for (int m = 0; m < 4; ++m)
#pragma unroll
    for (int n = 0; n < 4; ++n)
#pragma unroll
      for (int r = 0; r < 4; ++r) {
        int row = bm + wr + m * 16 + hi * 4 + r;
        int col = bn + wc + n * 16 + lo;
        if (OUT_BF16)
          ((short*)Cv)[(size_t)row * N + col] = f2bf(acc[m][n][r]);
        else
          ((float*)Cv)[(size_t)row * N + col] = acc[m][n][r];
      }
}

// ---------------- per-(token,head) RMSNorm + RoPE, bf16 in/out ----------------
template <int NHEAD, int IN_ROW, int IN_HS>
__global__ __launch_bounds__(256) void k_norm_rope(const short* __restrict__ xin,
                                                   const float* __restrict__ wn,
                                                   const float* __restrict__ cosb,
                                                   const float* __restrict__ sinb,
                                                   short* __restrict__ xout) {
  int blk = blockIdx.x;
  int h = blk % NHEAD;
  int ts = blk / NHEAD;
  int d = threadIdx.x;
  float x = bf2f(xin[(size_t)ts * IN_ROW + h * IN_HS + d]);
  float ss = x * x;
#pragma unroll
  for (int m = 32; m >= 1; m >>= 1) ss += __shfl_xor(ss, m);
  __shared__ float sred[4];
  __shared__ float sn[256];
  int wid = d >> 6;
  if ((d & 63) == 0) sred[wid] = ss;
  __syncthreads();
  float tot = sred[0] + sred[1] + sred[2] + sred[3];
  float nv = x * rsqrtf(tot * (1.0f / 256.0f) + 1e-6f) * (1.0f + wn[d]);
  sn[d] = nv;
  __syncthreads();
  float o;
  if (d < 128) {
    float c = cosb[(size_t)ts * 128 + d];
    float s = sinb[(size_t)ts * 128 + d];
    o = (d < 64) ? (nv * c - sn[d + 64] * s) : (nv * c + sn[d - 64] * s);
  } else {
    o = nv;
  }
  xout[(size_t)blk * 256 + d] = f2bf(o);
}

// ---------------- GQA causal flash attention + sigmoid gate ----------------
// 256 blocks (1/CU), 4 waves, QBLK=64 (16 rows/wave), KVBLK=64.
// Each block runs TWO q-tiles sequentially (qt=pair and 31-pair) -> exactly 33 tile-iters
// per block (perfect balance). K/V double-buffered in LDS via global_load_lds width-16
// with XOR-swizzled (chunk ^= row&7) layout: linear LDS dest + pre-swizzled global source
// + swizzled ds_read addresses (T2 both-sides). Batched fragment reads for ILP.
// LDS: K 2x32KB + V 2x32KB + Ps 9216 = 140288 B -> 1 block/CU by construction.
#define ATTN_LDS 140288
__global__ __launch_bounds__(256, 1) void k_attn(const short* __restrict__ qb,
                                                 const short* __restrict__ kb,
                                                 const short* __restrict__ Vtg,
                                                 const short* __restrict__ qg,
                                                 short* __restrict__ og) {
  extern __shared__ char smem[];
  short* KbufS = (short*)smem;                     // 2 bufs x [64 rows][32 chunks x 8]
  short* VbufS = (short*)(smem + 65536);           // 2 bufs x [256 rows][8 chunks x 8]
  short(*Ps)[16][72] = (short(*)[16][72])(smem + 131072);

  const int hg = blockIdx.x >> 4;
  const int pair = blockIdx.x & 15;
  const int b = hg >> 3, h = hg & 7, kvh = h >> 2;
  const int tid = threadIdx.x;
  const int w = tid >> 6, lane = tid & 63, lo = lane & 15, hi = lane >> 4;
  const int swz = lo & 7;  // row&7 for all fragment rows (row = X*16 + lo)

  const short* kbase = kb + ((size_t)(b * S_) * NKV_ + kvh) * HD_;  // K rows stride 512
  const short* vbase = Vtg + (size_t)(b * 2 + kvh) * 256 * 2048;    // V^T rows stride 2048

  // staging helpers: thread handles 8 chunk-slots for K and 8 for V per tile
  auto stage = [&](int kv0, int nb) {
#pragma unroll
    for (int rnd = 0; rnd < 8; ++rnd) {
      int i = rnd * 256 + tid;
      {  // K: slot i -> row = i>>5, chunk c = i&31 ; content = K[row][c ^ (row&7)]
        int row = i >> 5, c = i & 31;
        const short* src = kbase + (size_t)(kv0 + row) * 512 + ((c ^ (row & 7)) * 8);
        gl16(src, smem + (size_t)nb * 32768 + (size_t)i * 16);
      }
      {  // V: slot i -> row = i>>3, chunk c = i&7 ; content = V^T[row][kv0 + (c^(row&7))*8]
        int row = i >> 3, c = i & 7;
        const short* src = vbase + (size_t)row * 2048 + kv0 + ((c ^ (row & 7)) * 8);
        gl16(src, smem + 65536 + (size_t)nb * 32768 + (size_t)i * 16);
      }
    }
  };

#pragma unroll 1
  for (int ph = 0; ph < 2; ++ph) {
    const int qt = ph ? (31 - pair) : pair;
    const int q0 = qt * 64;
    const int ntiles = qt + 1;

    // Q fragments: A-layout (m=lane&15 -> q-row, k=(lane>>4)*8+j)
    s16x8 qf[8];
    {
      size_t base = ((size_t)((b * S_ + q0 + w * 16 + lo) * NH_) + h) * HD_;
#pragma unroll
      for (int t = 0; t < 8; ++t) qf[t] = *(const s16x8*)&qb[base + t * 32 + hi * 8];
    }
    f32x4 acc[16];
#pragma unroll
    for (int t = 0; t < 16; ++t) acc[t] = (f32x4){0.f, 0.f, 0.f, 0.f};
    float m_run[4], l_run[4];
#pragma unroll
    for (int r = 0; r < 4; ++r) { m_run[r] = -1e30f; l_run[r] = 0.f; }

    stage(0, 0);
    __syncthreads();

    int n = 0;
#pragma unroll 1
    for (int it = 0; it < ntiles; ++it) {
      const int kv0 = it * 64;
      if (it + 1 < ntiles) stage(kv0 + 64, n ^ 1);  // async loads fly under compute

      const short* Kb = KbufS + n * 16384;
      const short* Vb = VbufS + n * 16384;

      // S = Q @ K^T over HD=256 ; batched fragment reads per nt
      f32x4 sacc[4] = {};
#pragma unroll
      for (int nt = 0; nt < 4; ++nt) {
        s16x8 kf[8];
#pragma unroll
        for (int t = 0; t < 8; ++t)
          kf[t] = *(const s16x8*)&Kb[(nt * 16 + lo) * 256 + (((t * 4 + hi) ^ swz) * 8)];
#pragma unroll
        for (int t = 0; t < 8; ++t)
          sacc[nt] = __builtin_amdgcn_mfma_f32_16x16x32_bf16(qf[t], kf[t], sacc[nt], 0, 0, 0);
      }

      // online softmax: rows = q0 + w*16 + hi*4 + r, cols = kv0 + nt*16 + lo
      float fs[4];
#pragma unroll
      for (int r = 0; r < 4; ++r) {
        int row = q0 + w * 16 + hi * 4 + r;
        float sv[4];
#pragma unroll
        for (int nt = 0; nt < 4; ++nt) {
          float s = sacc[nt][r] * SCALE_;
          if (kv0 + nt * 16 + lo > row) s = -1e30f;
          sv[nt] = s;
        }
        float mx = fmaxf(fmaxf(sv[0], sv[1]), fmaxf(sv[2], sv[3]));
#pragma unroll
        for (int m = 8; m >= 1; m >>= 1) mx = fmaxf(mx, __shfl_xor(mx, m));
        float mnew = fmaxf(m_run[r], mx);
        fs[r] = __expf(m_run[r] - mnew);
        m_run[r] = mnew;
        float rs = 0.f;
#pragma unroll
        for (int nt = 0; nt < 4; ++nt) {
          sv[nt] = __expf(sv[nt] - mnew);
          rs += sv[nt];
        }
#pragma unroll
        for (int m = 8; m >= 1; m >>= 1) rs += __shfl_xor(rs, m);
        l_run[r] = l_run[r] * fs[r] + rs;
#pragma unroll
        for (int nt = 0; nt < 4; ++nt) Ps[w][hi * 4 + r][nt * 16 + lo] = f2bf(sv[nt]);
      }
#pragma unroll
      for (int t = 0; t < 16; ++t) {
        acc[t][0] *= fs[0];
        acc[t][1] *= fs[1];
        acc[t][2] *= fs[2];
        acc[t][3] *= fs[3];
      }
      // PV: A = P rows (via per-wave LDS), B = V^T fragments ; batched reads
#pragma unroll
      for (int ks = 0; ks < 2; ++ks) {
        s16x8 pa = *(const s16x8*)&Ps[w][lo][ks * 32 + hi * 8];
#pragma unroll
        for (int g = 0; g < 2; ++g) {
          s16x8 vf[8];
#pragma unroll
          for (int u = 0; u < 8; ++u) {
            int t = g * 8 + u;
            vf[u] = *(const s16x8*)&Vb[(t * 16 + lo) * 64 + (((ks * 4 + hi) ^ swz) * 8)];
          }
#pragma unroll
          for (int u = 0; u < 8; ++u) {
            int t = g * 8 + u;
            acc[t] = __builtin_amdgcn_mfma_f32_16x16x32_bf16(pa, vf[u], acc[t], 0, 0, 0);
          }
        }
      }
      __syncthreads();  // drains global_load_lds (vmcnt) + LDS; next buf ready
      n ^= 1;
    }

    // epilogue: normalize, sigmoid gate, store bf16
    float inv[4];
#pragma unroll
    for (int r = 0; r < 4; ++r) inv[r] = 1.0f / l_run[r];
#pragma unroll
    for (int t = 0; t < 16; ++t)
#pragma unroll
      for (int r = 0; r < 4; ++r) {
        int row = q0 + w * 16 + hi * 4 + r;
        int hd = t * 16 + lo;
        float o = acc[t][r] * inv[r];
        float g = bf2f(qg[(size_t)(b * S_ + row) * 4096 + h * 512 + 256 + hd]);
        float sg = 1.0f / (1.0f + __expf(-g));
        og[(size_t)(b * S_ + row) * 2048 + h * 256 + hd] = f2bf(o * sg);
      }
  }
}

extern "C" void kernel_launch(void* const* d_in, const int* in_sizes, int n_in, void* d_out,
                              int out_size, void* d_ws, size_t ws_size, hipStream_t stream) {
  const float* hidden = (const float*)d_in[0];
  const float* cosb = (const float*)d_in[1];
  const float* sinb = (const float*)d_in[2];
  const float* Wq = (const float*)d_in[3];
  const float* Wk = (const float*)d_in[4];
  const float* Wv = (const float*)d_in[5];
  const float* Wo = (const float*)d_in[6];
  const float* qw = (const float*)d_in[7];
  const float* kw = (const float*)d_in[8];
  float* out = (float*)d_out;

  char* ws = (char*)d_ws;
  size_t off = 0;
  auto alloc = [&](size_t bytes) {
    void* p = ws + off;
    off += (bytes + 255) & ~(size_t)255;
    return p;
  };
  short* hb = (short*)alloc((size_t)TOK_ * HID_ * 2);
  short* WqT = (short*)alloc((size_t)4096 * 1024 * 2);
  short* kvT = (short*)alloc((size_t)1024 * 1024 * 2);
  short* WoT = (short*)alloc((size_t)1024 * 2048 * 2);
  short* qg = (short*)alloc((size_t)TOK_ * 4096 * 2);
  short* kvp = (short*)alloc((size_t)TOK_ * 1024 * 2);
  short* qb = (short*)alloc((size_t)TOK_ * 2048 * 2);
  short* kb = (short*)alloc((size_t)TOK_ * 512 * 2);
  short* og = (short*)alloc((size_t)TOK_ * 2048 * 2);
  short* Vtg = WqT;  // reuse: WqT dead after GEMM1
  (void)ws_size;
  (void)in_sizes;
  (void)n_in;
  (void)out_size;

  hipFuncSetAttribute((const void*)k_attn, hipFuncAttributeMaxDynamicSharedMemorySize,
                      ATTN_LDS);

  k_cast<<<(TOK_ * HID_ + 255) / 256, 256, 0, stream>>>(hidden, hb, TOK_ * HID_);
  k_wtrans<<<dim3(4096 / 32, 1024 / 32), 256, 0, stream>>>(Wq, WqT, 1024, 4096);
  k_wtrans<<<dim3(512 / 32, 1024 / 32), 256, 0, stream>>>(Wk, kvT, 1024, 512);
  k_wtrans<<<dim3(512 / 32, 1024 / 32), 256, 0, stream>>>(Wv, kvT + 512 * 1024, 1024, 512);
  k_wtrans<<<dim3(1024 / 32, 2048 / 32), 256, 0, stream>>>(Wo, WoT, 2048, 1024);

  k_gemm_bt<1><<<dim3(32, 32), 256, 0, stream>>>(hb, WqT, qg, 4096, 4096, 1024);
  k_gemm_bt<1><<<dim3(8, 32), 256, 0, stream>>>(hb, kvT, kvp, 4096, 1024, 1024);

  k_norm_rope<NH_, 4096, 512><<<TOK_ * NH_, 256, 0, stream>>>(qg, qw, cosb, sinb, qb);
  k_norm_rope<NKV_, 1024, 256><<<TOK_ * NKV_, 256, 0, stream>>>(kvp, kw, cosb, sinb, kb);
  k_vtrans<<<dim3(64, 8, 4), 256, 0, stream>>>(kvp, Vtg);

  k_attn<<<256, 256, ATTN_LDS, stream>>>(qb, kb, Vtg, qg, og);

  k_gemm_bt<0><<<dim3(8, 32), 256, 0, stream>>>(og, WoT, out, 4096, 1024, 2048);
}

// Round 5
// 287.334 us; speedup vs baseline: 2.8172x; 1.0777x over previous
//
#include <hip/hip_runtime.h>
#include <cstdint>
#include <cstddef>

#define B_ 2
#define S_ 2048
#define HID_ 1024
#define NH_ 8
#define NKV_ 2
#define HD_ 256
#define ROT_ 128
#define TOK_ (B_ * S_)
#define SCALE_ 0.0625f

typedef __attribute__((ext_vector_type(8))) short s16x8;
typedef __attribute__((ext_vector_type(4))) float f32x4;

__device__ __forceinline__ float bf2f(short u) {
  unsigned t = ((unsigned)(unsigned short)u) << 16;
  float f;
  __builtin_memcpy(&f, &t, 4);
  return f;
}
__device__ __forceinline__ short f2bf(float f) {
  unsigned u;
  __builtin_memcpy(&u, &f, 4);
  u += 0x7fffu + ((u >> 16) & 1);
  return (short)(u >> 16);
}

// async global->LDS 16B (gfx950). LDS dest is wave-uniform base + lane*16.
__device__ __forceinline__ void gl16(const void* g, void* l) {
  __builtin_amdgcn_global_load_lds((const __attribute__((address_space(1))) int*)g,
                                   (__attribute__((address_space(3))) int*)l, 16, 0, 0);
}

// ---------------- elementwise cast fp32 -> bf16 ----------------
__global__ __launch_bounds__(256) void k_cast(const float* __restrict__ in,
                                              short* __restrict__ out, int n) {
  int i = blockIdx.x * 256 + threadIdx.x;
  if (i < n) out[i] = f2bf(in[i]);
}

// ---------------- tiled transpose + cast: in[R][C] fp32 -> out[C][R] bf16 ----------------
__global__ __launch_bounds__(256) void k_wtrans(const float* __restrict__ in,
                                                short* __restrict__ out, int R, int C) {
  __shared__ short tile[32][33];
  int tx = threadIdx.x & 31, ty = threadIdx.x >> 5;
  int r0 = blockIdx.y * 32, c0 = blockIdx.x * 32;
#pragma unroll
  for (int p = 0; p < 4; ++p)
    tile[ty + p * 8][tx] = f2bf(in[(size_t)(r0 + ty + p * 8) * C + c0 + tx]);
  __syncthreads();
#pragma unroll
  for (int p = 0; p < 4; ++p)
    out[(size_t)(c0 + ty + p * 8) * R + r0 + tx] = tile[tx][ty + p * 8];
}

// ---------------- V transpose: kvp v-part -> Vtg[b*2+kvh][256][2048] bf16 ----------------
__global__ __launch_bounds__(256) void k_vtrans(const short* __restrict__ kvp,
                                                short* __restrict__ Vtg) {
  __shared__ short tile[32][33];
  int bh = blockIdx.z;
  int b = bh >> 1, kvh = bh & 1;
  int s0 = blockIdx.x * 32, d0 = blockIdx.y * 32;
  int tx = threadIdx.x & 31, ty = threadIdx.x >> 5;
#pragma unroll
  for (int p = 0; p < 4; ++p) {
    int sr = ty + p * 8;
    tile[sr][tx] = kvp[(size_t)(b * S_ + s0 + sr) * 1024 + 512 + kvh * 256 + d0 + tx];
  }
  __syncthreads();
#pragma unroll
  for (int p = 0; p < 4; ++p) {
    int dr = ty + p * 8;
    Vtg[((size_t)bh * 256 + d0 + dr) * 2048 + s0 + tx] = tile[tx][dr];
  }
}

// ---------------- GEMM: C[M][N] = A[M][K] (bf16) @ Bt[N][K]^T (bf16) ----------------
// m97-class: 128x128 tile, BK=64, global_load_lds width-16 staging with XOR-swizzled
// layout (linear LDS dest + pre-swizzled global src + swizzled ds_read), 2 barriers/K-tile.
// Swizzled chunk: slot(row,c) holds X[row][(c^(row&7))*8 ..+8); read chunk (kk*4+hi)^(row&7)
// -> 64 lanes spread over all 32 banks (2-way max, free).
template <int OUT_BF16>
__global__ __launch_bounds__(256) void k_gemm_bt(const short* __restrict__ A,
                                                 const short* __restrict__ Bt,
                                                 void* __restrict__ Cv, int M, int N, int K) {
  __shared__ short As[128 * 64];
  __shared__ short Bs[128 * 64];
  const int tid = threadIdx.x;
  const int bm = blockIdx.y * 128, bn = blockIdx.x * 128;
  const int w = tid >> 6, lane = tid & 63, lo = lane & 15, hi = lane >> 4;
  const int wr = (w >> 1) * 64, wc = (w & 1) * 64;
  f32x4 acc[4][4] = {};
  for (int k0 = 0; k0 < K; k0 += 64) {
    // stage A and B tiles: 4 rounds each, 16B per thread per round
#pragma unroll
    for (int rnd = 0; rnd < 4; ++rnd) {
      int i = rnd * 256 + tid;  // slot 0..1023
      int row = i >> 3, c = i & 7;
      int src_col = (c ^ (row & 7)) * 8;
      gl16(&A[(size_t)(bm + row) * K + k0 + src_col], (char*)As + (size_t)i * 16);
      gl16(&Bt[(size_t)(bn + row) * K + k0 + src_col], (char*)Bs + (size_t)i * 16);
    }
    __syncthreads();  // drains vmcnt (gl_lds) before reads
    s16x8 af[2][4], bfr[2][4];
#pragma unroll
    for (int kk = 0; kk < 2; ++kk) {
#pragma unroll
      for (int m = 0; m < 4; ++m) {
        int row = wr + m * 16 + lo;
        af[kk][m] = *(const s16x8*)&As[row * 64 + (((kk * 4 + hi) ^ (row & 7)) * 8)];
      }
#pragma unroll
      for (int n = 0; n < 4; ++n) {
        int row = wc + n * 16 + lo;
        bfr[kk][n] = *(const s16x8*)&Bs[row * 64 + (((kk * 4 + hi) ^ (row & 7)) * 8)];
      }
    }
#pragma unroll
    for (int kk = 0; kk < 2; ++kk)
#pragma unroll
      for (int m = 0; m < 4; ++m)
#pragma unroll
        for (int n = 0; n < 4; ++n)
          acc[m][n] =
              __builtin_amdgcn_mfma_f32_16x16x32_bf16(af[kk][m], bfr[kk][n], acc[m][n], 0, 0, 0);
    __syncthreads();  // all reads done before next stage overwrites
  }
#pragma unroll
  for (int m = 0; m < 4; ++m)
#pragma unroll
    for (int n = 0; n < 4; ++n)
#pragma unroll
      for (int r = 0; r < 4; ++r) {
        int row = bm + wr + m * 16 + hi * 4 + r;
        int col = bn + wc + n * 16 + lo;
        if (OUT_BF16)
          ((short*)Cv)[(size_t)row * N + col] = f2bf(acc[m][n][r]);
        else
          ((float*)Cv)[(size_t)row * N + col] = acc[m][n][r];
      }
}

// ---------------- per-(token,head) RMSNorm + RoPE, bf16 in/out ----------------
template <int NHEAD, int IN_ROW, int IN_HS>
__global__ __launch_bounds__(256) void k_norm_rope(const short* __restrict__ xin,
                                                   const float* __restrict__ wn,
                                                   const float* __restrict__ cosb,
                                                   const float* __restrict__ sinb,
                                                   short* __restrict__ xout) {
  int blk = blockIdx.x;
  int h = blk % NHEAD;
  int ts = blk / NHEAD;
  int d = threadIdx.x;
  float x = bf2f(xin[(size_t)ts * IN_ROW + h * IN_HS + d]);
  float ss = x * x;
#pragma unroll
  for (int m = 32; m >= 1; m >>= 1) ss += __shfl_xor(ss, m);
  __shared__ float sred[4];
  __shared__ float sn[256];
  int wid = d >> 6;
  if ((d & 63) == 0) sred[wid] = ss;
  __syncthreads();
  float tot = sred[0] + sred[1] + sred[2] + sred[3];
  float nv = x * rsqrtf(tot * (1.0f / 256.0f) + 1e-6f) * (1.0f + wn[d]);
  sn[d] = nv;
  __syncthreads();
  float o;
  if (d < 128) {
    float c = cosb[(size_t)ts * 128 + d];
    float s = sinb[(size_t)ts * 128 + d];
    o = (d < 64) ? (nv * c - sn[d + 64] * s) : (nv * c + sn[d - 64] * s);
  } else {
    o = nv;
  }
  xout[(size_t)blk * 256 + d] = f2bf(o);
}

// ---------------- GQA causal flash attention + sigmoid gate ----------------
// 256 blocks (1/CU), 4 waves, QBLK=64 (16 rows/wave), KVBLK=64.
// Each block runs TWO q-tiles sequentially (qt=pair and 31-pair) -> exactly 33 tile-iters.
// K/V double-buffered via global_load_lds w16 with XOR-swizzled layout (T2 both-sides).
#define ATTN_LDS 140288
__global__ __launch_bounds__(256, 1) void k_attn(const short* __restrict__ qb,
                                                 const short* __restrict__ kb,
                                                 const short* __restrict__ Vtg,
                                                 const short* __restrict__ qg,
                                                 short* __restrict__ og) {
  extern __shared__ char smem[];
  short* KbufS = (short*)smem;            // 2 bufs x [64 rows][32 chunks x 8]
  short* VbufS = (short*)(smem + 65536);  // 2 bufs x [256 rows][8 chunks x 8]
  short(*Ps)[16][72] = (short(*)[16][72])(smem + 131072);

  const int hg = blockIdx.x >> 4;
  const int pair = blockIdx.x & 15;
  const int b = hg >> 3, h = hg & 7, kvh = h >> 2;
  const int tid = threadIdx.x;
  const int w = tid >> 6, lane = tid & 63, lo = lane & 15, hi = lane >> 4;
  const int swz = lo & 7;

  const short* kbase = kb + ((size_t)(b * S_) * NKV_ + kvh) * HD_;
  const short* vbase = Vtg + (size_t)(b * 2 + kvh) * 256 * 2048;

  auto stage = [&](int kv0, int nb) {
#pragma unroll
    for (int rnd = 0; rnd < 8; ++rnd) {
      int i = rnd * 256 + tid;
      {
        int row = i >> 5, c = i & 31;
        const short* src = kbase + (size_t)(kv0 + row) * 512 + ((c ^ (row & 7)) * 8);
        gl16(src, smem + (size_t)nb * 32768 + (size_t)i * 16);
      }
      {
        int row = i >> 3, c = i & 7;
        const short* src = vbase + (size_t)row * 2048 + kv0 + ((c ^ (row & 7)) * 8);
        gl16(src, smem + 65536 + (size_t)nb * 32768 + (size_t)i * 16);
      }
    }
  };

#pragma unroll 1
  for (int ph = 0; ph < 2; ++ph) {
    const int qt = ph ? (31 - pair) : pair;
    const int q0 = qt * 64;
    const int ntiles = qt + 1;

    s16x8 qf[8];
    {
      size_t base = ((size_t)((b * S_ + q0 + w * 16 + lo) * NH_) + h) * HD_;
#pragma unroll
      for (int t = 0; t < 8; ++t) qf[t] = *(const s16x8*)&qb[base + t * 32 + hi * 8];
    }
    f32x4 acc[16];
#pragma unroll
    for (int t = 0; t < 16; ++t) acc[t] = (f32x4){0.f, 0.f, 0.f, 0.f};
    float m_run[4], l_run[4];
#pragma unroll
    for (int r = 0; r < 4; ++r) { m_run[r] = -1e30f; l_run[r] = 0.f; }

    stage(0, 0);
    __syncthreads();

    int n = 0;
#pragma unroll 1
    for (int it = 0; it < ntiles; ++it) {
      const int kv0 = it * 64;
      if (it + 1 < ntiles) stage(kv0 + 64, n ^ 1);

      const short* Kb = KbufS + n * 16384;
      const short* Vb = VbufS + n * 16384;

      f32x4 sacc[4] = {};
#pragma unroll
      for (int nt = 0; nt < 4; ++nt) {
        s16x8 kf[8];
#pragma unroll
        for (int t = 0; t < 8; ++t)
          kf[t] = *(const s16x8*)&Kb[(nt * 16 + lo) * 256 + (((t * 4 + hi) ^ swz) * 8)];
#pragma unroll
        for (int t = 0; t < 8; ++t)
          sacc[nt] = __builtin_amdgcn_mfma_f32_16x16x32_bf16(qf[t], kf[t], sacc[nt], 0, 0, 0);
      }

      float fs[4];
#pragma unroll
      for (int r = 0; r < 4; ++r) {
        int row = q0 + w * 16 + hi * 4 + r;
        float sv[4];
#pragma unroll
        for (int nt = 0; nt < 4; ++nt) {
          float s = sacc[nt][r] * SCALE_;
          if (kv0 + nt * 16 + lo > row) s = -1e30f;
          sv[nt] = s;
        }
        float mx = fmaxf(fmaxf(sv[0], sv[1]), fmaxf(sv[2], sv[3]));
#pragma unroll
        for (int m = 8; m >= 1; m >>= 1) mx = fmaxf(mx, __shfl_xor(mx, m));
        float mnew = fmaxf(m_run[r], mx);
        fs[r] = __expf(m_run[r] - mnew);
        m_run[r] = mnew;
        float rs = 0.f;
#pragma unroll
        for (int nt = 0; nt < 4; ++nt) {
          sv[nt] = __expf(sv[nt] - mnew);
          rs += sv[nt];
        }
#pragma unroll
        for (int m = 8; m >= 1; m >>= 1) rs += __shfl_xor(rs, m);
        l_run[r] = l_run[r] * fs[r] + rs;
#pragma unroll
        for (int nt = 0; nt < 4; ++nt) Ps[w][hi * 4 + r][nt * 16 + lo] = f2bf(sv[nt]);
      }
#pragma unroll
      for (int t = 0; t < 16; ++t) {
        acc[t][0] *= fs[0];
        acc[t][1] *= fs[1];
        acc[t][2] *= fs[2];
        acc[t][3] *= fs[3];
      }
#pragma unroll
      for (int ks = 0; ks < 2; ++ks) {
        s16x8 pa = *(const s16x8*)&Ps[w][lo][ks * 32 + hi * 8];
#pragma unroll
        for (int g = 0; g < 2; ++g) {
          s16x8 vf[8];
#pragma unroll
          for (int u = 0; u < 8; ++u) {
            int t = g * 8 + u;
            vf[u] = *(const s16x8*)&Vb[(t * 16 + lo) * 64 + (((ks * 4 + hi) ^ swz) * 8)];
          }
#pragma unroll
          for (int u = 0; u < 8; ++u) {
            int t = g * 8 + u;
            acc[t] = __builtin_amdgcn_mfma_f32_16x16x32_bf16(pa, vf[u], acc[t], 0, 0, 0);
          }
        }
      }
      __syncthreads();
      n ^= 1;
    }

    float inv[4];
#pragma unroll
    for (int r = 0; r < 4; ++r) inv[r] = 1.0f / l_run[r];
#pragma unroll
    for (int t = 0; t < 16; ++t)
#pragma unroll
      for (int r = 0; r < 4; ++r) {
        int row = q0 + w * 16 + hi * 4 + r;
        int hd = t * 16 + lo;
        float o = acc[t][r] * inv[r];
        float g = bf2f(qg[(size_t)(b * S_ + row) * 4096 + h * 512 + 256 + hd]);
        float sg = 1.0f / (1.0f + __expf(-g));
        og[(size_t)(b * S_ + row) * 2048 + h * 256 + hd] = f2bf(o * sg);
      }
  }
}

extern "C" void kernel_launch(void* const* d_in, const int* in_sizes, int n_in, void* d_out,
                              int out_size, void* d_ws, size_t ws_size, hipStream_t stream) {
  const float* hidden = (const float*)d_in[0];
  const float* cosb = (const float*)d_in[1];
  const float* sinb = (const float*)d_in[2];
  const float* Wq = (const float*)d_in[3];
  const float* Wk = (const float*)d_in[4];
  const float* Wv = (const float*)d_in[5];
  const float* Wo = (const float*)d_in[6];
  const float* qw = (const float*)d_in[7];
  const float* kw = (const float*)d_in[8];
  float* out = (float*)d_out;

  char* ws = (char*)d_ws;
  size_t off = 0;
  auto alloc = [&](size_t bytes) {
    void* p = ws + off;
    off += (bytes + 255) & ~(size_t)255;
    return p;
  };
  short* hb = (short*)alloc((size_t)TOK_ * HID_ * 2);
  short* WqT = (short*)alloc((size_t)4096 * 1024 * 2);
  short* kvT = (short*)alloc((size_t)1024 * 1024 * 2);
  short* WoT = (short*)alloc((size_t)1024 * 2048 * 2);
  short* qg = (short*)alloc((size_t)TOK_ * 4096 * 2);
  short* kvp = (short*)alloc((size_t)TOK_ * 1024 * 2);
  short* qb = (short*)alloc((size_t)TOK_ * 2048 * 2);
  short* kb = (short*)alloc((size_t)TOK_ * 512 * 2);
  short* og = (short*)alloc((size_t)TOK_ * 2048 * 2);
  short* Vtg = WqT;  // reuse: WqT dead after GEMM1
  (void)ws_size;
  (void)in_sizes;
  (void)n_in;
  (void)out_size;

  hipFuncSetAttribute((const void*)k_attn, hipFuncAttributeMaxDynamicSharedMemorySize,
                      ATTN_LDS);

  k_cast<<<(TOK_ * HID_ + 255) / 256, 256, 0, stream>>>(hidden, hb, TOK_ * HID_);
  k_wtrans<<<dim3(4096 / 32, 1024 / 32), 256, 0, stream>>>(Wq, WqT, 1024, 4096);
  k_wtrans<<<dim3(512 / 32, 1024 / 32), 256, 0, stream>>>(Wk, kvT, 1024, 512);
  k_wtrans<<<dim3(512 / 32, 1024 / 32), 256, 0, stream>>>(Wv, kvT + 512 * 1024, 1024, 512);
  k_wtrans<<<dim3(1024 / 32, 2048 / 32), 256, 0, stream>>>(Wo, WoT, 2048, 1024);

  k_gemm_bt<1><<<dim3(32, 32), 256, 0, stream>>>(hb, WqT, qg, 4096, 4096, 1024);
  k_gemm_bt<1><<<dim3(8, 32), 256, 0, stream>>>(hb, kvT, kvp, 4096, 1024, 1024);

  k_norm_rope<NH_, 4096, 512><<<TOK_ * NH_, 256, 0, stream>>>(qg, qw, cosb, sinb, qb);
  k_norm_rope<NKV_, 1024, 256><<<TOK_ * NKV_, 256, 0, stream>>>(kvp, kw, cosb, sinb, kb);
  k_vtrans<<<dim3(64, 8, 4), 256, 0, stream>>>(kvp, Vtg);

  k_attn<<<256, 256, ATTN_LDS, stream>>>(qb, kb, Vtg, qg, og);

  k_gemm_bt<0><<<dim3(8, 32), 256, 0, stream>>>(og, WoT, out, 4096, 1024, 2048);
}

// Round 6
// 282.632 us; speedup vs baseline: 2.8640x; 1.0166x over previous
//
#include <hip/hip_runtime.h>
#include <cstdint>
#include <cstddef>

#define B_ 2
#define S_ 2048
#define HID_ 1024
#define NH_ 8
#define NKV_ 2
#define HD_ 256
#define ROT_ 128
#define TOK_ (B_ * S_)
#define SCALE_ 0.0625f

typedef __attribute__((ext_vector_type(8))) short s16x8;
typedef __attribute__((ext_vector_type(4))) float f32x4;

__device__ __forceinline__ float bf2f(short u) {
  unsigned t = ((unsigned)(unsigned short)u) << 16;
  float f;
  __builtin_memcpy(&f, &t, 4);
  return f;
}
__device__ __forceinline__ short f2bf(float f) {
  unsigned u;
  __builtin_memcpy(&u, &f, 4);
  u += 0x7fffu + ((u >> 16) & 1);
  return (short)(u >> 16);
}

// async global->LDS 16B (gfx950). LDS dest is wave-uniform base + lane*16.
__device__ __forceinline__ void gl16(const void* g, void* l) {
  __builtin_amdgcn_global_load_lds((const __attribute__((address_space(1))) int*)g,
                                   (__attribute__((address_space(3))) int*)l, 16, 0, 0);
}

// ---------------- elementwise cast fp32 -> bf16 ----------------
__global__ __launch_bounds__(256) void k_cast(const float* __restrict__ in,
                                              short* __restrict__ out, int n) {
  int i = blockIdx.x * 256 + threadIdx.x;
  if (i < n) out[i] = f2bf(in[i]);
}

// ---------------- tiled transpose + cast: in[R][C] fp32 -> out[C][R] bf16 ----------------
__global__ __launch_bounds__(256) void k_wtrans(const float* __restrict__ in,
                                                short* __restrict__ out, int R, int C) {
  __shared__ short tile[32][33];
  int tx = threadIdx.x & 31, ty = threadIdx.x >> 5;
  int r0 = blockIdx.y * 32, c0 = blockIdx.x * 32;
#pragma unroll
  for (int p = 0; p < 4; ++p)
    tile[ty + p * 8][tx] = f2bf(in[(size_t)(r0 + ty + p * 8) * C + c0 + tx]);
  __syncthreads();
#pragma unroll
  for (int p = 0; p < 4; ++p)
    out[(size_t)(c0 + ty + p * 8) * R + r0 + tx] = tile[tx][ty + p * 8];
}

// ---------------- V transpose: kvp v-part -> Vtg[b*2+kvh][256][2048] bf16 ----------------
__global__ __launch_bounds__(256) void k_vtrans(const short* __restrict__ kvp,
                                                short* __restrict__ Vtg) {
  __shared__ short tile[32][33];
  int bh = blockIdx.z;
  int b = bh >> 1, kvh = bh & 1;
  int s0 = blockIdx.x * 32, d0 = blockIdx.y * 32;
  int tx = threadIdx.x & 31, ty = threadIdx.x >> 5;
#pragma unroll
  for (int p = 0; p < 4; ++p) {
    int sr = ty + p * 8;
    tile[sr][tx] = kvp[(size_t)(b * S_ + s0 + sr) * 1024 + 512 + kvh * 256 + d0 + tx];
  }
  __syncthreads();
#pragma unroll
  for (int p = 0; p < 4; ++p) {
    int dr = ty + p * 8;
    Vtg[((size_t)bh * 256 + d0 + dr) * 2048 + s0 + tx] = tile[tx][dr];
  }
}

// ---------------- GEMM: C[M][N] = A[M][K] (bf16) @ Bt[N][K]^T (bf16) ----------------
// m97-class: 128x128 tile, BK=64, global_load_lds width-16 staging with XOR-swizzled
// layout (linear LDS dest + pre-swizzled global src + swizzled ds_read), 2 barriers/K-tile.
template <int OUT_BF16>
__global__ __launch_bounds__(256) void k_gemm_bt(const short* __restrict__ A,
                                                 const short* __restrict__ Bt,
                                                 void* __restrict__ Cv, int M, int N, int K) {
  __shared__ short As[128 * 64];
  __shared__ short Bs[128 * 64];
  const int tid = threadIdx.x;
  const int bm = blockIdx.y * 128, bn = blockIdx.x * 128;
  const int w = tid >> 6, lane = tid & 63, lo = lane & 15, hi = lane >> 4;
  const int wr = (w >> 1) * 64, wc = (w & 1) * 64;
  f32x4 acc[4][4] = {};
  for (int k0 = 0; k0 < K; k0 += 64) {
#pragma unroll
    for (int rnd = 0; rnd < 4; ++rnd) {
      int i = rnd * 256 + tid;
      int row = i >> 3, c = i & 7;
      int src_col = (c ^ (row & 7)) * 8;
      gl16(&A[(size_t)(bm + row) * K + k0 + src_col], (char*)As + (size_t)i * 16);
      gl16(&Bt[(size_t)(bn + row) * K + k0 + src_col], (char*)Bs + (size_t)i * 16);
    }
    __syncthreads();
    s16x8 af[2][4], bfr[2][4];
#pragma unroll
    for (int kk = 0; kk < 2; ++kk) {
#pragma unroll
      for (int m = 0; m < 4; ++m) {
        int row = wr + m * 16 + lo;
        af[kk][m] = *(const s16x8*)&As[row * 64 + (((kk * 4 + hi) ^ (row & 7)) * 8)];
      }
#pragma unroll
      for (int n = 0; n < 4; ++n) {
        int row = wc + n * 16 + lo;
        bfr[kk][n] = *(const s16x8*)&Bs[row * 64 + (((kk * 4 + hi) ^ (row & 7)) * 8)];
      }
    }
#pragma unroll
    for (int kk = 0; kk < 2; ++kk)
#pragma unroll
      for (int m = 0; m < 4; ++m)
#pragma unroll
        for (int n = 0; n < 4; ++n)
          acc[m][n] =
              __builtin_amdgcn_mfma_f32_16x16x32_bf16(af[kk][m], bfr[kk][n], acc[m][n], 0, 0, 0);
    __syncthreads();
  }
#pragma unroll
  for (int m = 0; m < 4; ++m)
#pragma unroll
    for (int n = 0; n < 4; ++n)
#pragma unroll
      for (int r = 0; r < 4; ++r) {
        int row = bm + wr + m * 16 + hi * 4 + r;
        int col = bn + wc + n * 16 + lo;
        if (OUT_BF16)
          ((short*)Cv)[(size_t)row * N + col] = f2bf(acc[m][n][r]);
        else
          ((float*)Cv)[(size_t)row * N + col] = acc[m][n][r];
      }
}

// ---------------- per-(token,head) RMSNorm + RoPE, bf16 in/out ----------------
template <int NHEAD, int IN_ROW, int IN_HS>
__global__ __launch_bounds__(256) void k_norm_rope(const short* __restrict__ xin,
                                                   const float* __restrict__ wn,
                                                   const float* __restrict__ cosb,
                                                   const float* __restrict__ sinb,
                                                   short* __restrict__ xout) {
  int blk = blockIdx.x;
  int h = blk % NHEAD;
  int ts = blk / NHEAD;
  int d = threadIdx.x;
  float x = bf2f(xin[(size_t)ts * IN_ROW + h * IN_HS + d]);
  float ss = x * x;
#pragma unroll
  for (int m = 32; m >= 1; m >>= 1) ss += __shfl_xor(ss, m);
  __shared__ float sred[4];
  __shared__ float sn[256];
  int wid = d >> 6;
  if ((d & 63) == 0) sred[wid] = ss;
  __syncthreads();
  float tot = sred[0] + sred[1] + sred[2] + sred[3];
  float nv = x * rsqrtf(tot * (1.0f / 256.0f) + 1e-6f) * (1.0f + wn[d]);
  sn[d] = nv;
  __syncthreads();
  float o;
  if (d < 128) {
    float c = cosb[(size_t)ts * 128 + d];
    float s = sinb[(size_t)ts * 128 + d];
    o = (d < 64) ? (nv * c - sn[d + 64] * s) : (nv * c + sn[d - 64] * s);
  } else {
    o = nv;
  }
  xout[(size_t)blk * 256 + d] = f2bf(o);
}

// ---------------- GQA causal flash attention + sigmoid gate ----------------
// 256 blocks, 8 waves (512 thr), QBLK=128 (16 rows/wave), KVBLK=64 double-buffered.
// 2 waves/SIMD for TLP; each K/V tile read feeds 128 q-rows (half the tile-visits of
// QBLK=64). XCD-aware block permutation: blocks sharing a (b,kvh) K/V stream (2MB,
// fits 4MB XCD L2) map to a dedicated XCD pair via blockIdx % 8.
// LDS: K 2x32KB + V 2x32KB + Ps[8][16][72] = 149504 B -> 1 block/CU.
#define ATTN_LDS 149504
__global__ __launch_bounds__(512, 1) void k_attn(const short* __restrict__ qb,
                                                 const short* __restrict__ kb,
                                                 const short* __restrict__ Vtg,
                                                 const short* __restrict__ qg,
                                                 short* __restrict__ og) {
  extern __shared__ char smem[];
  short* KbufS = (short*)smem;            // 2 bufs x [64 rows][32 chunks x 8]
  short* VbufS = (short*)(smem + 65536);  // 2 bufs x [256 rows][8 chunks x 8]
  short(*Ps)[16][72] = (short(*)[16][72])(smem + 131072);

  // XCD-aware decode: xcd = blockIdx % 8 (HW round-robin); (b,kvh) pair p = xcd/2.
  const int raw = blockIdx.x;
  const int xcd = raw & 7, slot = raw >> 3;  // slot 0..31
  const int p = xcd >> 1, side = xcd & 1;
  const int id = side * 32 + slot;  // 0..63 within pair
  const int hgi = id & 3, qt = id >> 2;  // 4 heads x 16 q-tiles
  const int b = p >> 1, kvh = p & 1, h = kvh * 4 + hgi;
  const int q0 = qt * 128;
  const int tid = threadIdx.x;
  const int w = tid >> 6, lane = tid & 63, lo = lane & 15, hi = lane >> 4;
  const int swz = lo & 7;

  const short* kbase = kb + ((size_t)(b * S_) * NKV_ + kvh) * HD_;  // K rows stride 512
  const short* vbase = Vtg + (size_t)(b * 2 + kvh) * 256 * 2048;    // V^T rows stride 2048

  // stage one KVBLK=64 tile: K 2048 slots + V 2048 slots, 4 rounds x 512 threads each
  auto stage = [&](int kv0, int nb) {
#pragma unroll
    for (int rnd = 0; rnd < 4; ++rnd) {
      int i = rnd * 512 + tid;
      {  // K slot i: row = i>>5, chunk c = i&31; holds K[row][(c^(row&7))*8..+8)
        int row = i >> 5, c = i & 31;
        const short* src = kbase + (size_t)(kv0 + row) * 512 + ((c ^ (row & 7)) * 8);
        gl16(src, smem + (size_t)nb * 32768 + (size_t)i * 16);
      }
      {  // V slot i: row = i>>3, chunk c = i&7; holds V^T[row][kv0+(c^(row&7))*8..)
        int row = i >> 3, c = i & 7;
        const short* src = vbase + (size_t)row * 2048 + kv0 + ((c ^ (row & 7)) * 8);
        gl16(src, smem + 65536 + (size_t)nb * 32768 + (size_t)i * 16);
      }
    }
  };

  // Q fragments: A-layout (m=lane&15 -> q-row, k=(lane>>4)*8+j)
  s16x8 qf[8];
  {
    size_t base = ((size_t)((b * S_ + q0 + w * 16 + lo) * NH_) + h) * HD_;
#pragma unroll
    for (int t = 0; t < 8; ++t) qf[t] = *(const s16x8*)&qb[base + t * 32 + hi * 8];
  }
  f32x4 acc[16];
#pragma unroll
  for (int t = 0; t < 16; ++t) acc[t] = (f32x4){0.f, 0.f, 0.f, 0.f};
  float m_run[4], l_run[4];
#pragma unroll
  for (int r = 0; r < 4; ++r) { m_run[r] = -1e30f; l_run[r] = 0.f; }

  stage(0, 0);
  __syncthreads();

  const int ntiles = 2 * qt + 2;  // KVBLK=64 covers [0, q0+128)
  int n = 0;
#pragma unroll 1
  for (int it = 0; it < ntiles; ++it) {
    const int kv0 = it * 64;
    if (it + 1 < ntiles) stage(kv0 + 64, n ^ 1);  // async loads fly under compute

    const short* Kb = KbufS + n * 16384;
    const short* Vb = VbufS + n * 16384;

    // S = Q @ K^T over HD=256 ; batched fragment reads per nt
    f32x4 sacc[4] = {};
#pragma unroll
    for (int nt = 0; nt < 4; ++nt) {
      s16x8 kf[8];
#pragma unroll
      for (int t = 0; t < 8; ++t)
        kf[t] = *(const s16x8*)&Kb[(nt * 16 + lo) * 256 + (((t * 4 + hi) ^ swz) * 8)];
#pragma unroll
      for (int t = 0; t < 8; ++t)
        sacc[nt] = __builtin_amdgcn_mfma_f32_16x16x32_bf16(qf[t], kf[t], sacc[nt], 0, 0, 0);
    }

    // online softmax: rows = q0 + w*16 + hi*4 + r, cols = kv0 + nt*16 + lo
    float fs[4];
#pragma unroll
    for (int r = 0; r < 4; ++r) {
      int row = q0 + w * 16 + hi * 4 + r;
      float sv[4];
#pragma unroll
      for (int nt = 0; nt < 4; ++nt) {
        float s = sacc[nt][r] * SCALE_;
        if (kv0 + nt * 16 + lo > row) s = -1e30f;
        sv[nt] = s;
      }
      float mx = fmaxf(fmaxf(sv[0], sv[1]), fmaxf(sv[2], sv[3]));
#pragma unroll
      for (int m = 8; m >= 1; m >>= 1) mx = fmaxf(mx, __shfl_xor(mx, m));
      float mnew = fmaxf(m_run[r], mx);
      fs[r] = __expf(m_run[r] - mnew);
      m_run[r] = mnew;
      float rs = 0.f;
#pragma unroll
      for (int nt = 0; nt < 4; ++nt) {
        sv[nt] = __expf(sv[nt] - mnew);
        rs += sv[nt];
      }
#pragma unroll
      for (int m = 8; m >= 1; m >>= 1) rs += __shfl_xor(rs, m);
      l_run[r] = l_run[r] * fs[r] + rs;
#pragma unroll
      for (int nt = 0; nt < 4; ++nt) Ps[w][hi * 4 + r][nt * 16 + lo] = f2bf(sv[nt]);
    }
#pragma unroll
    for (int t = 0; t < 16; ++t) {
      acc[t][0] *= fs[0];
      acc[t][1] *= fs[1];
      acc[t][2] *= fs[2];
      acc[t][3] *= fs[3];
    }
    // PV: A = P rows (per-wave LDS roundtrip), B = V^T fragments ; batched reads
#pragma unroll
    for (int ks = 0; ks < 2; ++ks) {
      s16x8 pa = *(const s16x8*)&Ps[w][lo][ks * 32 + hi * 8];
#pragma unroll
      for (int g = 0; g < 2; ++g) {
        s16x8 vf[8];
#pragma unroll
        for (int u = 0; u < 8; ++u) {
          int t = g * 8 + u;
          vf[u] = *(const s16x8*)&Vb[(t * 16 + lo) * 64 + (((ks * 4 + hi) ^ swz) * 8)];
        }
#pragma unroll
        for (int u = 0; u < 8; ++u) {
          int t = g * 8 + u;
          acc[t] = __builtin_amdgcn_mfma_f32_16x16x32_bf16(pa, vf[u], acc[t], 0, 0, 0);
        }
      }
    }
    __syncthreads();  // drains gl_lds (vmcnt) + LDS reads; next buf ready
    n ^= 1;
  }

  // epilogue: normalize, sigmoid gate, store bf16
  float inv[4];
#pragma unroll
  for (int r = 0; r < 4; ++r) inv[r] = 1.0f / l_run[r];
#pragma unroll
  for (int t = 0; t < 16; ++t)
#pragma unroll
    for (int r = 0; r < 4; ++r) {
      int row = q0 + w * 16 + hi * 4 + r;
      int hd = t * 16 + lo;
      float o = acc[t][r] * inv[r];
      float g = bf2f(qg[(size_t)(b * S_ + row) * 4096 + h * 512 + 256 + hd]);
      float sg = 1.0f / (1.0f + __expf(-g));
      og[(size_t)(b * S_ + row) * 2048 + h * 256 + hd] = f2bf(o * sg);
    }
}

extern "C" void kernel_launch(void* const* d_in, const int* in_sizes, int n_in, void* d_out,
                              int out_size, void* d_ws, size_t ws_size, hipStream_t stream) {
  const float* hidden = (const float*)d_in[0];
  const float* cosb = (const float*)d_in[1];
  const float* sinb = (const float*)d_in[2];
  const float* Wq = (const float*)d_in[3];
  const float* Wk = (const float*)d_in[4];
  const float* Wv = (const float*)d_in[5];
  const float* Wo = (const float*)d_in[6];
  const float* qw = (const float*)d_in[7];
  const float* kw = (const float*)d_in[8];
  float* out = (float*)d_out;

  char* ws = (char*)d_ws;
  size_t off = 0;
  auto alloc = [&](size_t bytes) {
    void* p = ws + off;
    off += (bytes + 255) & ~(size_t)255;
    return p;
  };
  short* hb = (short*)alloc((size_t)TOK_ * HID_ * 2);
  short* WqT = (short*)alloc((size_t)4096 * 1024 * 2);
  short* kvT = (short*)alloc((size_t)1024 * 1024 * 2);
  short* WoT = (short*)alloc((size_t)1024 * 2048 * 2);
  short* qg = (short*)alloc((size_t)TOK_ * 4096 * 2);
  short* kvp = (short*)alloc((size_t)TOK_ * 1024 * 2);
  short* qb = (short*)alloc((size_t)TOK_ * 2048 * 2);
  short* kb = (short*)alloc((size_t)TOK_ * 512 * 2);
  short* og = (short*)alloc((size_t)TOK_ * 2048 * 2);
  short* Vtg = WqT;  // reuse: WqT dead after GEMM1
  (void)ws_size;
  (void)in_sizes;
  (void)n_in;
  (void)out_size;

  hipFuncSetAttribute((const void*)k_attn, hipFuncAttributeMaxDynamicSharedMemorySize,
                      ATTN_LDS);

  k_cast<<<(TOK_ * HID_ + 255) / 256, 256, 0, stream>>>(hidden, hb, TOK_ * HID_);
  k_wtrans<<<dim3(4096 / 32, 1024 / 32), 256, 0, stream>>>(Wq, WqT, 1024, 4096);
  k_wtrans<<<dim3(512 / 32, 1024 / 32), 256, 0, stream>>>(Wk, kvT, 1024, 512);
  k_wtrans<<<dim3(512 / 32, 1024 / 32), 256, 0, stream>>>(Wv, kvT + 512 * 1024, 1024, 512);
  k_wtrans<<<dim3(1024 / 32, 2048 / 32), 256, 0, stream>>>(Wo, WoT, 2048, 1024);

  k_gemm_bt<1><<<dim3(32, 32), 256, 0, stream>>>(hb, WqT, qg, 4096, 4096, 1024);
  k_gemm_bt<1><<<dim3(8, 32), 256, 0, stream>>>(hb, kvT, kvp, 4096, 1024, 1024);

  k_norm_rope<NH_, 4096, 512><<<TOK_ * NH_, 256, 0, stream>>>(qg, qw, cosb, sinb, qb);
  k_norm_rope<NKV_, 1024, 256><<<TOK_ * NKV_, 256, 0, stream>>>(kvp, kw, cosb, sinb, kb);
  k_vtrans<<<dim3(64, 8, 4), 256, 0, stream>>>(kvp, Vtg);

  k_attn<<<256, 512, ATTN_LDS, stream>>>(qb, kb, Vtg, qg, og);

  k_gemm_bt<0><<<dim3(8, 32), 256, 0, stream>>>(og, WoT, out, 4096, 1024, 2048);
}

// Round 7
// 259.566 us; speedup vs baseline: 3.1186x; 1.0889x over previous
//
#include <hip/hip_runtime.h>
#include <cstdint>
#include <cstddef>

#define B_ 2
#define S_ 2048
#define HID_ 1024
#define NH_ 8
#define NKV_ 2
#define HD_ 256
#define ROT_ 128
#define TOK_ (B_ * S_)
#define SCALE_ 0.0625f

typedef __attribute__((ext_vector_type(8))) short s16x8;
typedef __attribute__((ext_vector_type(4))) float f32x4;

__device__ __forceinline__ float bf2f(short u) {
  unsigned t = ((unsigned)(unsigned short)u) << 16;
  float f;
  __builtin_memcpy(&f, &t, 4);
  return f;
}
__device__ __forceinline__ short f2bf(float f) {
  unsigned u;
  __builtin_memcpy(&u, &f, 4);
  u += 0x7fffu + ((u >> 16) & 1);
  return (short)(u >> 16);
}

// async global->LDS 16B (gfx950). LDS dest is wave-uniform base + lane*16.
__device__ __forceinline__ void gl16(const void* g, void* l) {
  __builtin_amdgcn_global_load_lds((const __attribute__((address_space(1))) int*)g,
                                   (__attribute__((address_space(3))) int*)l, 16, 0, 0);
}

// ---------------- elementwise cast fp32 -> bf16 ----------------
__global__ __launch_bounds__(256) void k_cast(const float* __restrict__ in,
                                              short* __restrict__ out, int n) {
  int i = blockIdx.x * 256 + threadIdx.x;
  if (i < n) out[i] = f2bf(in[i]);
}

// ---------------- tiled transpose + cast: in[R][C] fp32 -> out[C][R] bf16 ----------------
__global__ __launch_bounds__(256) void k_wtrans(const float* __restrict__ in,
                                                short* __restrict__ out, int R, int C) {
  __shared__ short tile[32][33];
  int tx = threadIdx.x & 31, ty = threadIdx.x >> 5;
  int r0 = blockIdx.y * 32, c0 = blockIdx.x * 32;
#pragma unroll
  for (int p = 0; p < 4; ++p)
    tile[ty + p * 8][tx] = f2bf(in[(size_t)(r0 + ty + p * 8) * C + c0 + tx]);
  __syncthreads();
#pragma unroll
  for (int p = 0; p < 4; ++p)
    out[(size_t)(c0 + ty + p * 8) * R + r0 + tx] = tile[tx][ty + p * 8];
}

// ---------------- V transpose: kvp v-part -> Vtg[b*2+kvh][256][2048] bf16 ----------------
__global__ __launch_bounds__(256) void k_vtrans(const short* __restrict__ kvp,
                                                short* __restrict__ Vtg) {
  __shared__ short tile[32][33];
  int bh = blockIdx.z;
  int b = bh >> 1, kvh = bh & 1;
  int s0 = blockIdx.x * 32, d0 = blockIdx.y * 32;
  int tx = threadIdx.x & 31, ty = threadIdx.x >> 5;
#pragma unroll
  for (int p = 0; p < 4; ++p) {
    int sr = ty + p * 8;
    tile[sr][tx] = kvp[(size_t)(b * S_ + s0 + sr) * 1024 + 512 + kvh * 256 + d0 + tx];
  }
  __syncthreads();
#pragma unroll
  for (int p = 0; p < 4; ++p) {
    int dr = ty + p * 8;
    Vtg[((size_t)bh * 256 + d0 + dr) * 2048 + s0 + tx] = tile[tx][dr];
  }
}

// ---------------- GEMM 128x128 (for skinny N): BK=64, gl16 staging, XOR swizzle ------
template <int OUT_BF16>
__global__ __launch_bounds__(256) void k_gemm_bt(const short* __restrict__ A,
                                                 const short* __restrict__ Bt,
                                                 void* __restrict__ Cv, int M, int N, int K) {
  __shared__ short As[128 * 64];
  __shared__ short Bs[128 * 64];
  const int tid = threadIdx.x;
  const int bm = blockIdx.y * 128, bn = blockIdx.x * 128;
  const int w = tid >> 6, lane = tid & 63, lo = lane & 15, hi = lane >> 4;
  const int wr = (w >> 1) * 64, wc = (w & 1) * 64;
  f32x4 acc[4][4] = {};
  for (int k0 = 0; k0 < K; k0 += 64) {
#pragma unroll
    for (int rnd = 0; rnd < 4; ++rnd) {
      int i = rnd * 256 + tid;
      int row = i >> 3, c = i & 7;
      int src_col = (c ^ (row & 7)) * 8;
      gl16(&A[(size_t)(bm + row) * K + k0 + src_col], (char*)As + (size_t)i * 16);
      gl16(&Bt[(size_t)(bn + row) * K + k0 + src_col], (char*)Bs + (size_t)i * 16);
    }
    __syncthreads();
    s16x8 af[2][4], bfr[2][4];
#pragma unroll
    for (int kk = 0; kk < 2; ++kk) {
#pragma unroll
      for (int m = 0; m < 4; ++m) {
        int row = wr + m * 16 + lo;
        af[kk][m] = *(const s16x8*)&As[row * 64 + (((kk * 4 + hi) ^ (row & 7)) * 8)];
      }
#pragma unroll
      for (int n = 0; n < 4; ++n) {
        int row = wc + n * 16 + lo;
        bfr[kk][n] = *(const s16x8*)&Bs[row * 64 + (((kk * 4 + hi) ^ (row & 7)) * 8)];
      }
    }
#pragma unroll
    for (int kk = 0; kk < 2; ++kk)
#pragma unroll
      for (int m = 0; m < 4; ++m)
#pragma unroll
        for (int n = 0; n < 4; ++n)
          acc[m][n] =
              __builtin_amdgcn_mfma_f32_16x16x32_bf16(af[kk][m], bfr[kk][n], acc[m][n], 0, 0, 0);
    __syncthreads();
  }
#pragma unroll
  for (int m = 0; m < 4; ++m)
#pragma unroll
    for (int n = 0; n < 4; ++n)
#pragma unroll
      for (int r = 0; r < 4; ++r) {
        int row = bm + wr + m * 16 + hi * 4 + r;
        int col = bn + wc + n * 16 + lo;
        if (OUT_BF16)
          ((short*)Cv)[(size_t)row * N + col] = f2bf(acc[m][n][r]);
        else
          ((float*)Cv)[(size_t)row * N + col] = acc[m][n][r];
      }
}

// ---------------- GEMM 256x256, 8 waves, BK=64 (2-phase structure) ----------------
// Per wave: 128x64 output (8x4 frags). 64 MFMA : 24 ds_read_b128 per K-tile.
template <int OUT_BF16>
__global__ __launch_bounds__(512) void k_gemm256(const short* __restrict__ A,
                                                 const short* __restrict__ Bt,
                                                 void* __restrict__ Cv, int M, int N, int K) {
  __shared__ short As[256 * 64];
  __shared__ short Bs[256 * 64];
  const int tid = threadIdx.x;
  const int bm = blockIdx.y * 256, bn = blockIdx.x * 256;
  const int w = tid >> 6, lane = tid & 63, lo = lane & 15, hi = lane >> 4;
  const int wr = (w >> 2) * 128, wc = (w & 3) * 64;
  f32x4 acc[8][4] = {};
  for (int k0 = 0; k0 < K; k0 += 64) {
#pragma unroll
    for (int rnd = 0; rnd < 4; ++rnd) {
      int i = rnd * 512 + tid;  // slot 0..2047
      int row = i >> 3, c = i & 7;
      int src_col = (c ^ (row & 7)) * 8;
      gl16(&A[(size_t)(bm + row) * K + k0 + src_col], (char*)As + (size_t)i * 16);
      gl16(&Bt[(size_t)(bn + row) * K + k0 + src_col], (char*)Bs + (size_t)i * 16);
    }
    __syncthreads();
#pragma unroll
    for (int kk = 0; kk < 2; ++kk) {
      s16x8 af[8], bfr[4];
#pragma unroll
      for (int m = 0; m < 8; ++m) {
        int row = wr + m * 16 + lo;
        af[m] = *(const s16x8*)&As[row * 64 + (((kk * 4 + hi) ^ (row & 7)) * 8)];
      }
#pragma unroll
      for (int n = 0; n < 4; ++n) {
        int row = wc + n * 16 + lo;
        bfr[n] = *(const s16x8*)&Bs[row * 64 + (((kk * 4 + hi) ^ (row & 7)) * 8)];
      }
#pragma unroll
      for (int m = 0; m < 8; ++m)
#pragma unroll
        for (int n = 0; n < 4; ++n)
          acc[m][n] = __builtin_amdgcn_mfma_f32_16x16x32_bf16(af[m], bfr[n], acc[m][n], 0, 0, 0);
    }
    __syncthreads();
  }
#pragma unroll
  for (int m = 0; m < 8; ++m)
#pragma unroll
    for (int n = 0; n < 4; ++n)
#pragma unroll
      for (int r = 0; r < 4; ++r) {
        int row = bm + wr + m * 16 + hi * 4 + r;
        int col = bn + wc + n * 16 + lo;
        if (OUT_BF16)
          ((short*)Cv)[(size_t)row * N + col] = f2bf(acc[m][n][r]);
        else
          ((float*)Cv)[(size_t)row * N + col] = acc[m][n][r];
      }
}

// ---------------- per-(token,head) RMSNorm + RoPE, bf16 in/out ----------------
template <int NHEAD, int IN_ROW, int IN_HS>
__global__ __launch_bounds__(256) void k_norm_rope(const short* __restrict__ xin,
                                                   const float* __restrict__ wn,
                                                   const float* __restrict__ cosb,
                                                   const float* __restrict__ sinb,
                                                   short* __restrict__ xout) {
  int blk = blockIdx.x;
  int h = blk % NHEAD;
  int ts = blk / NHEAD;
  int d = threadIdx.x;
  float x = bf2f(xin[(size_t)ts * IN_ROW + h * IN_HS + d]);
  float ss = x * x;
#pragma unroll
  for (int m = 32; m >= 1; m >>= 1) ss += __shfl_xor(ss, m);
  __shared__ float sred[4];
  __shared__ float sn[256];
  int wid = d >> 6;
  if ((d & 63) == 0) sred[wid] = ss;
  __syncthreads();
  float tot = sred[0] + sred[1] + sred[2] + sred[3];
  float nv = x * rsqrtf(tot * (1.0f / 256.0f) + 1e-6f) * (1.0f + wn[d]);
  sn[d] = nv;
  __syncthreads();
  float o;
  if (d < 128) {
    float c = cosb[(size_t)ts * 128 + d];
    float s = sinb[(size_t)ts * 128 + d];
    o = (d < 64) ? (nv * c - sn[d + 64] * s) : (nv * c + sn[d - 64] * s);
  } else {
    o = nv;
  }
  xout[(size_t)blk * 256 + d] = f2bf(o);
}

// ---------------- GQA causal flash attention + sigmoid gate ----------------
// 256 blocks, 8 waves, QBLK=128 (16 rows/wave), KVBLK=64 double-buffered, gl16+swizzle.
// SWAPPED QK^T: mfma(K,Q) -> S^T, q-row lane-local => in-register softmax:
// 15 fmax + 2 shfl_xor (vs 8-deep chains), no P LDS roundtrip (cvt_pk + 16 bpermute),
// T13 defer-rescale THR=8. LDS: K 2x32KB + V 2x32KB = 131072 -> 1 block/CU.
#define ATTN_LDS 131072
__global__ __launch_bounds__(512, 1) void k_attn(const short* __restrict__ qb,
                                                 const short* __restrict__ kb,
                                                 const short* __restrict__ Vtg,
                                                 const short* __restrict__ qg,
                                                 short* __restrict__ og) {
  extern __shared__ char smem[];
  short* KbufS = (short*)smem;            // 2 bufs x [64 rows][32 chunks x 8]
  short* VbufS = (short*)(smem + 65536);  // 2 bufs x [256 rows][8 chunks x 8]

  // XCD-aware decode: xcd = blockIdx % 8; (b,kvh) stream pinned to an XCD pair.
  const int raw = blockIdx.x;
  const int xcd = raw & 7, slot = raw >> 3;
  const int p = xcd >> 1, side = xcd & 1;
  const int id = side * 32 + slot;
  const int hgi = id & 3, qt = id >> 2;
  const int b = p >> 1, kvh = p & 1, h = kvh * 4 + hgi;
  const int q0 = qt * 128;
  const int tid = threadIdx.x;
  const int w = tid >> 6, lane = tid & 63, lo = lane & 15, hi = lane >> 4;
  const int swz = lo & 7;

  const short* kbase = kb + ((size_t)(b * S_) * NKV_ + kvh) * HD_;
  const short* vbase = Vtg + (size_t)(b * 2 + kvh) * 256 * 2048;

  auto stage = [&](int kv0, int nb) {
#pragma unroll
    for (int rnd = 0; rnd < 4; ++rnd) {
      int i = rnd * 512 + tid;
      {
        int row = i >> 5, c = i & 31;
        const short* src = kbase + (size_t)(kv0 + row) * 512 + ((c ^ (row & 7)) * 8);
        gl16(src, smem + (size_t)nb * 32768 + (size_t)i * 16);
      }
      {
        int row = i >> 3, c = i & 7;
        const short* src = vbase + (size_t)row * 2048 + kv0 + ((c ^ (row & 7)) * 8);
        gl16(src, smem + 65536 + (size_t)nb * 32768 + (size_t)i * 16);
      }
    }
  };

  // Q fragments (B-operand now; same addressing): n=lane&15 -> q-row, k=(lane>>4)*8+j
  s16x8 qf[8];
  {
    size_t base = ((size_t)((b * S_ + q0 + w * 16 + lo) * NH_) + h) * HD_;
#pragma unroll
    for (int t = 0; t < 8; ++t) qf[t] = *(const s16x8*)&qb[base + t * 32 + hi * 8];
  }
  f32x4 acc[16];
#pragma unroll
  for (int t = 0; t < 16; ++t) acc[t] = (f32x4){0.f, 0.f, 0.f, 0.f};
  // softmax state per lane, row = q0 + w*16 + lo (4 identical copies across hi)
  float m_run = -1e30f, l_run = 0.f;
  const int qrow = q0 + w * 16 + lo;

  stage(0, 0);
  __syncthreads();

  const int ntiles = 2 * qt + 2;
  int n = 0;
#pragma unroll 1
  for (int it = 0; it < ntiles; ++it) {
    const int kv0 = it * 64;
    if (it + 1 < ntiles) stage(kv0 + 64, n ^ 1);

    const short* Kb = KbufS + n * 16384;
    const short* Vb = VbufS + n * 16384;

    // S^T = K @ Q^T over HD=256 (swapped operands). Per lane: col=lo=q-row,
    // rows kv = kv0 + nt*16 + hi*4 + r  -> 16 P values lane-local per q-row.
    f32x4 sacc[4] = {};
#pragma unroll
    for (int nt = 0; nt < 4; ++nt) {
      s16x8 kf[8];
#pragma unroll
      for (int t = 0; t < 8; ++t)
        kf[t] = *(const s16x8*)&Kb[(nt * 16 + lo) * 256 + (((t * 4 + hi) ^ swz) * 8)];
#pragma unroll
      for (int t = 0; t < 8; ++t)
        sacc[nt] = __builtin_amdgcn_mfma_f32_16x16x32_bf16(kf[t], qf[t], sacc[nt], 0, 0, 0);
    }

    // in-register softmax
    float pv[4][4];
    float mx = -1e30f;
#pragma unroll
    for (int nt = 0; nt < 4; ++nt)
#pragma unroll
      for (int r = 0; r < 4; ++r) {
        int kv = kv0 + nt * 16 + hi * 4 + r;
        float s = sacc[nt][r] * SCALE_;
        if (kv > qrow) s = -1e30f;
        pv[nt][r] = s;
        mx = fmaxf(mx, s);
      }
    mx = fmaxf(mx, __shfl_xor(mx, 16));
    mx = fmaxf(mx, __shfl_xor(mx, 32));
    if (!__all(mx <= m_run + 8.f)) {  // T13 defer-rescale
      float mnew = fmaxf(m_run, mx);
      float fs = __expf(m_run - mnew);
      m_run = mnew;
      l_run *= fs;
      float f0 = __shfl(fs, 4 * hi + 0);
      float f1 = __shfl(fs, 4 * hi + 1);
      float f2 = __shfl(fs, 4 * hi + 2);
      float f3 = __shfl(fs, 4 * hi + 3);
#pragma unroll
      for (int t = 0; t < 16; ++t) {
        acc[t][0] *= f0;
        acc[t][1] *= f1;
        acc[t][2] *= f2;
        acc[t][3] *= f3;
      }
    }
    float rs = 0.f;
#pragma unroll
    for (int nt = 0; nt < 4; ++nt)
#pragma unroll
      for (int r = 0; r < 4; ++r) {
        pv[nt][r] = __expf(pv[nt][r] - m_run);
        rs += pv[nt][r];
      }
    rs += __shfl_xor(rs, 16);
    rs += __shfl_xor(rs, 32);
    l_run += rs;

    // pack P to bf16 pairs: pk0[nt] = (p[nt][0], p[nt][1]), pk1[nt] = (p[nt][2], p[nt][3])
    int pk0[4], pk1[4];
#pragma unroll
    for (int nt = 0; nt < 4; ++nt) {
      asm("v_cvt_pk_bf16_f32 %0, %1, %2" : "=v"(pk0[nt]) : "v"(pv[nt][0]), "v"(pv[nt][1]));
      asm("v_cvt_pk_bf16_f32 %0, %1, %2" : "=v"(pk1[nt]) : "v"(pv[nt][2]), "v"(pv[nt][3]));
    }

    // PV: A-frag P[m=q=lo][k=kv=ks*32+hi*8+j] gathered via bpermute from S^T owners
#pragma unroll
    for (int ks = 0; ks < 2; ++ks) {
      int pw[4];
#pragma unroll
      for (int dw = 0; dw < 4; ++dw) {
        int srcl = (2 * (hi & 1) + (dw >> 1)) * 16 + lo;
        int vA = __shfl((dw & 1) ? pk1[2 * ks] : pk0[2 * ks], srcl);
        int vB = __shfl((dw & 1) ? pk1[2 * ks + 1] : pk0[2 * ks + 1], srcl);
        pw[dw] = (hi & 2) ? vB : vA;
      }
      s16x8 pa;
      __builtin_memcpy(&pa, pw, 16);
#pragma unroll
      for (int g = 0; g < 2; ++g) {
        s16x8 vf[8];
#pragma unroll
        for (int u = 0; u < 8; ++u) {
          int t = g * 8 + u;
          vf[u] = *(const s16x8*)&Vb[(t * 16 + lo) * 64 + (((ks * 4 + hi) ^ swz) * 8)];
        }
#pragma unroll
        for (int u = 0; u < 8; ++u) {
          int t = g * 8 + u;
          acc[t] = __builtin_amdgcn_mfma_f32_16x16x32_bf16(pa, vf[u], acc[t], 0, 0, 0);
        }
      }
    }
    __syncthreads();
    n ^= 1;
  }

  // epilogue: normalize (l gathered per acc row), sigmoid gate, store bf16
  float linv[4];
#pragma unroll
  for (int r = 0; r < 4; ++r) linv[r] = 1.0f / __shfl(l_run, 4 * hi + r);
#pragma unroll
  for (int t = 0; t < 16; ++t)
#pragma unroll
    for (int r = 0; r < 4; ++r) {
      int row = q0 + w * 16 + hi * 4 + r;
      int hd = t * 16 + lo;
      float o = acc[t][r] * linv[r];
      float g = bf2f(qg[(size_t)(b * S_ + row) * 4096 + h * 512 + 256 + hd]);
      float sg = 1.0f / (1.0f + __expf(-g));
      og[(size_t)(b * S_ + row) * 2048 + h * 256 + hd] = f2bf(o * sg);
    }
}

extern "C" void kernel_launch(void* const* d_in, const int* in_sizes, int n_in, void* d_out,
                              int out_size, void* d_ws, size_t ws_size, hipStream_t stream) {
  const float* hidden = (const float*)d_in[0];
  const float* cosb = (const float*)d_in[1];
  const float* sinb = (const float*)d_in[2];
  const float* Wq = (const float*)d_in[3];
  const float* Wk = (const float*)d_in[4];
  const float* Wv = (const float*)d_in[5];
  const float* Wo = (const float*)d_in[6];
  const float* qw = (const float*)d_in[7];
  const float* kw = (const float*)d_in[8];
  float* out = (float*)d_out;

  char* ws = (char*)d_ws;
  size_t off = 0;
  auto alloc = [&](size_t bytes) {
    void* p = ws + off;
    off += (bytes + 255) & ~(size_t)255;
    return p;
  };
  short* hb = (short*)alloc((size_t)TOK_ * HID_ * 2);
  short* WqT = (short*)alloc((size_t)4096 * 1024 * 2);
  short* kvT = (short*)alloc((size_t)1024 * 1024 * 2);
  short* WoT = (short*)alloc((size_t)1024 * 2048 * 2);
  short* qg = (short*)alloc((size_t)TOK_ * 4096 * 2);
  short* kvp = (short*)alloc((size_t)TOK_ * 1024 * 2);
  short* qb = (short*)alloc((size_t)TOK_ * 2048 * 2);
  short* kb = (short*)alloc((size_t)TOK_ * 512 * 2);
  short* og = (short*)alloc((size_t)TOK_ * 2048 * 2);
  short* Vtg = WqT;  // reuse: WqT dead after GEMM1
  (void)ws_size;
  (void)in_sizes;
  (void)n_in;
  (void)out_size;

  hipFuncSetAttribute((const void*)k_attn, hipFuncAttributeMaxDynamicSharedMemorySize,
                      ATTN_LDS);

  k_cast<<<(TOK_ * HID_ + 255) / 256, 256, 0, stream>>>(hidden, hb, TOK_ * HID_);
  k_wtrans<<<dim3(4096 / 32, 1024 / 32), 256, 0, stream>>>(Wq, WqT, 1024, 4096);
  k_wtrans<<<dim3(512 / 32, 1024 / 32), 256, 0, stream>>>(Wk, kvT, 1024, 512);
  k_wtrans<<<dim3(512 / 32, 1024 / 32), 256, 0, stream>>>(Wv, kvT + 512 * 1024, 1024, 512);
  k_wtrans<<<dim3(1024 / 32, 2048 / 32), 256, 0, stream>>>(Wo, WoT, 2048, 1024);

  k_gemm256<1><<<dim3(16, 16), 512, 0, stream>>>(hb, WqT, qg, 4096, 4096, 1024);
  k_gemm_bt<1><<<dim3(8, 32), 256, 0, stream>>>(hb, kvT, kvp, 4096, 1024, 1024);

  k_norm_rope<NH_, 4096, 512><<<TOK_ * NH_, 256, 0, stream>>>(qg, qw, cosb, sinb, qb);
  k_norm_rope<NKV_, 1024, 256><<<TOK_ * NKV_, 256, 0, stream>>>(kvp, kw, cosb, sinb, kb);
  k_vtrans<<<dim3(64, 8, 4), 256, 0, stream>>>(kvp, Vtg);

  k_attn<<<256, 512, ATTN_LDS, stream>>>(qb, kb, Vtg, qg, og);

  k_gemm_bt<0><<<dim3(8, 32), 256, 0, stream>>>(og, WoT, out, 4096, 1024, 2048);
}